// Round 3
// baseline (3054.599 us; speedup 1.0000x reference)
//
#include <hip/hip_runtime.h>

typedef __attribute__((ext_vector_type(8))) short short8;
typedef __attribute__((ext_vector_type(4))) float floatx4;

#define NCH 74          // chunks per layer
#define CH 32768        // edges per chunk
#define NB 1563         // coarse buckets (128 keys each)
#define NK 200000       // keys = node*4 + r
#define SCAN_T (2 * NB * NCH)
#define SCAN_NBLK 226   // ceil(SCAN_T/1024)

__device__ __forceinline__ unsigned short f2bf(float f) {
  unsigned u = __float_as_uint(f);
  u += 0x7FFFu + ((u >> 16) & 1u);
  return (unsigned short)(u >> 16);
}

// ---- prep: feat->bf16; W1 -> W1T [3][n=128][k=128]; W2 -> W2T [3][n=64][k=128] ----
__global__ __launch_bounds__(256) void prep_k(
    const float* __restrict__ feat, const float* __restrict__ W1,
    const float* __restrict__ W2, unsigned short* __restrict__ featb,
    unsigned short* __restrict__ w1t, unsigned short* __restrict__ w2t) {
  int tid = blockIdx.x * 256 + threadIdx.x;
  if (tid < 1600000) {
    float4 v = ((const float4*)feat)[tid];
    ushort4 o;
    o.x = f2bf(v.x); o.y = f2bf(v.y); o.z = f2bf(v.z); o.w = f2bf(v.w);
    ((ushort4*)featb)[tid] = o;
  } else if (tid < 1600000 + 49152) {
    int t = tid - 1600000;
    int r = t >> 14, rem = t & 16383, n = rem >> 7, k = rem & 127;
    w1t[t] = f2bf(W1[(r << 14) + (k << 7) + n]);
  } else if (tid < 1600000 + 49152 + 24576) {
    int t = tid - 1649152;
    int r = t >> 13, rem = t & 8191, n = rem >> 7, k = rem & 127;
    w2t[t] = f2bf(W2[(r << 13) + (k << 6) + n]);
  }
}

// ---- pass A: per-chunk bucket histograms -> ghist[layer][b][c] ----
__global__ __launch_bounds__(256) void count_k(
    const int* __restrict__ ed1, const int* __restrict__ ed2,
    int* __restrict__ ghist) {
  __shared__ int h[NB];
  int tid = threadIdx.x;
  int layer = blockIdx.x >= NCH;
  int c = blockIdx.x - layer * NCH;
  const int* ed = layer ? ed2 : ed1;
  for (int i = tid; i < NB; i += 256) h[i] = 0;
  __syncthreads();
  int j0 = c * CH;
  for (int it = 0; it < CH / 256; ++it) {
    int j = j0 + it * 256 + tid;
    if (j < 2400000) {
      int key = ed[j] * 4 + j / 800000;
      atomicAdd(&h[key >> 7], 1);
    }
  }
  __syncthreads();
  int base = layer * NB * NCH;
  for (int b = tid; b < NB; b += 256) ghist[base + b * NCH + c] = h[b];
}

// ---- scan: 3-phase exclusive prefix over ghist (in place) ----
__global__ __launch_bounds__(256) void scan1_k(const int* __restrict__ g,
                                               int* __restrict__ blksum) {
  __shared__ int ws_[4];
  int tid = threadIdx.x;
  int base = blockIdx.x * 1024 + tid * 4;
  int s = 0;
#pragma unroll
  for (int k = 0; k < 4; ++k) { int i = base + k; if (i < SCAN_T) s += g[i]; }
#pragma unroll
  for (int o = 32; o > 0; o >>= 1) s += __shfl_down(s, o);
  if ((tid & 63) == 0) ws_[tid >> 6] = s;
  __syncthreads();
  if (tid == 0) blksum[blockIdx.x] = ws_[0] + ws_[1] + ws_[2] + ws_[3];
}
__global__ __launch_bounds__(64) void scan2_k(int* __restrict__ blksum) {
  int lane = threadIdx.x;
  int carry = 0;
  for (int g0 = 0; g0 < SCAN_NBLK; g0 += 64) {
    int i = g0 + lane;
    int v = (i < SCAN_NBLK) ? blksum[i] : 0;
    int inc = v;
#pragma unroll
    for (int o = 1; o < 64; o <<= 1) { int u = __shfl_up(inc, o); if (lane >= o) inc += u; }
    if (i < SCAN_NBLK) blksum[i] = carry + inc - v;
    carry += __shfl(inc, 63);
  }
}
__global__ __launch_bounds__(256) void scan3_k(int* __restrict__ g,
                                               const int* __restrict__ blksum) {
  __shared__ int wt[4];
  int tid = threadIdx.x, lane = tid & 63, w = tid >> 6;
  int base = blockIdx.x * 1024 + tid * 4;
  int v[4]; int s = 0;
#pragma unroll
  for (int k = 0; k < 4; ++k) { int i = base + k; v[k] = (i < SCAN_T) ? g[i] : 0; s += v[k]; }
  int inc = s;
#pragma unroll
  for (int o = 1; o < 64; o <<= 1) { int u = __shfl_up(inc, o); if (lane >= o) inc += u; }
  if (lane == 63) wt[w] = inc;
  __syncthreads();
  int woff = 0;
#pragma unroll
  for (int k = 0; k < 4; ++k) if (k < w) woff += wt[k];
  int excl = blksum[blockIdx.x] + woff + inc - s;
#pragma unroll
  for (int k = 0; k < 4; ++k) {
    int i = base + k;
    if (i < SCAN_T) g[i] = excl;
    excl += v[k];
  }
}

// ---- pass B: chunk-local LDS-cursor scatter -> sorted[] (packed src | ldst<<16) ----
__global__ __launch_bounds__(256) void scatter_k(
    const int* __restrict__ es1, const int* __restrict__ ed1,
    const int* __restrict__ es2, const int* __restrict__ ed2,
    const int* __restrict__ gbase, unsigned* __restrict__ sorted) {
  __shared__ int cur[NB];
  int tid = threadIdx.x;
  int layer = blockIdx.x >= NCH;
  int c = blockIdx.x - layer * NCH;
  const int* es = layer ? es2 : es1;
  const int* ed = layer ? ed2 : ed1;
  int gb = layer * NB * NCH;
  for (int b = tid; b < NB; b += 256) cur[b] = gbase[gb + b * NCH + c];
  __syncthreads();
  int j0 = c * CH;
  for (int it = 0; it < CH / 256; ++it) {
    int j = j0 + it * 256 + tid;
    if (j < 2400000) {
      int key = ed[j] * 4 + j / 800000;
      int pos = atomicAdd(&cur[key >> 7], 1);
      sorted[pos] = (unsigned)es[j] | ((unsigned)(key & 127) << 16);
    }
  }
}

// ---- layer-1 agg: one block per bucket, LDS f32 acc (de-interleaved), mean->bf16 ----
__global__ __launch_bounds__(512) void agg1_k(
    const int* __restrict__ gbase, const unsigned* __restrict__ sorted,
    const unsigned* __restrict__ featb4, unsigned* __restrict__ s1m4,
    int* __restrict__ cnt1g) {
  __shared__ float acc[16384];   // [128 keys][128 slots]  slot(d) = (d>>1) + (d&1)*64
  __shared__ int cnt[128];
  int tid = threadIdx.x, lane = tid & 63, wid = tid >> 6;
  int b = blockIdx.x;
  for (int i = tid; i < 16384; i += 512) acc[i] = 0.f;
  if (tid < 128) cnt[tid] = 0;
  __syncthreads();
  int start = gbase[b * NCH];
  int end = gbase[(b + 1) * NCH];   // b=NB-1 -> layer-2 start = 2.4M, correct
  for (int e = start + wid; e < end; e += 32) {   // 4-deep unroll across stride-8
    int e1 = e + 8, e2 = e + 16, e3 = e + 24;
    unsigned v0 = sorted[e];
    unsigned v1 = (e1 < end) ? sorted[e1] : 0u;
    unsigned v2 = (e2 < end) ? sorted[e2] : 0u;
    unsigned v3 = (e3 < end) ? sorted[e3] : 0u;
    unsigned p0 = featb4[((v0 & 0xFFFFu) << 6) + lane];
    unsigned p1 = (e1 < end) ? featb4[((v1 & 0xFFFFu) << 6) + lane] : 0u;
    unsigned p2 = (e2 < end) ? featb4[((v2 & 0xFFFFu) << 6) + lane] : 0u;
    unsigned p3 = (e3 < end) ? featb4[((v3 & 0xFFFFu) << 6) + lane] : 0u;
    int l0 = v0 >> 16;
    unsafeAtomicAdd(&acc[(l0 << 7) + lane], __uint_as_float(p0 << 16));
    unsafeAtomicAdd(&acc[(l0 << 7) + 64 + lane], __uint_as_float(p0 & 0xFFFF0000u));
    if (lane == 0) atomicAdd(&cnt[l0], 1);
    if (e1 < end) {
      int l1 = v1 >> 16;
      unsafeAtomicAdd(&acc[(l1 << 7) + lane], __uint_as_float(p1 << 16));
      unsafeAtomicAdd(&acc[(l1 << 7) + 64 + lane], __uint_as_float(p1 & 0xFFFF0000u));
      if (lane == 0) atomicAdd(&cnt[l1], 1);
    }
    if (e2 < end) {
      int l2 = v2 >> 16;
      unsafeAtomicAdd(&acc[(l2 << 7) + lane], __uint_as_float(p2 << 16));
      unsafeAtomicAdd(&acc[(l2 << 7) + 64 + lane], __uint_as_float(p2 & 0xFFFF0000u));
      if (lane == 0) atomicAdd(&cnt[l2], 1);
    }
    if (e3 < end) {
      int l3 = v3 >> 16;
      unsafeAtomicAdd(&acc[(l3 << 7) + lane], __uint_as_float(p3 << 16));
      unsafeAtomicAdd(&acc[(l3 << 7) + 64 + lane], __uint_as_float(p3 & 0xFFFF0000u));
      if (lane == 0) atomicAdd(&cnt[l3], 1);
    }
  }
  __syncthreads();
  for (int kk = wid; kk < 128; kk += 8) {
    int key = (b << 7) + kk;
    if (key >= NK) break;
    int node = key >> 2, r = key & 3;
    int cn = cnt[kk];
    float inv = 1.0f / fmaxf((float)cn, 1.0f);
    float lo = acc[(kk << 7) + lane] * inv;        // dim 2*lane
    float hi = acc[(kk << 7) + 64 + lane] * inv;   // dim 2*lane+1
    unsigned pk = ((unsigned)f2bf(hi) << 16) | (unsigned)f2bf(lo);
    s1m4[(r * 50000 + node) * 64 + lane] = pk;
    if (lane == 0) cnt1g[key] = cn;
  }
}

// ---- GEMM1: h = leaky( sum_r s1m_r @ W1_r + b1_r*[cnt>0] ), bf16 out ----
__global__ __launch_bounds__(256) void gemm1_k(
    const unsigned short* __restrict__ s1m, const int* __restrict__ cnt1g,
    const unsigned short* __restrict__ w1t, const float* __restrict__ b1,
    unsigned short* __restrict__ hb) {
  int lane = threadIdx.x & 63;
  int wave = threadIdx.x >> 6;
  int rbase = blockIdx.x * 64 + wave * 16;
  int arow = rbase + (lane & 15);
  int anode = arow < 50000 ? arow : 49999;
  int kg = lane >> 4;

  const floatx4 fzero = {0.f, 0.f, 0.f, 0.f};
  floatx4 acc[8];
#pragma unroll
  for (int f = 0; f < 8; ++f) acc[f] = fzero;

#pragma unroll
  for (int ks = 0; ks < 12; ++ks) {
    int r = ks >> 2;
    int k0 = ((ks & 3) << 5) + (kg << 3);
    short8 af = *(const short8*)(s1m + ((r * 50000 + anode) << 7) + k0);
#pragma unroll
    for (int f = 0; f < 8; ++f) {
      int n = (f << 4) + (lane & 15);
      short8 bf = *(const short8*)(w1t + (r << 14) + (n << 7) + k0);
      acc[f] = __builtin_amdgcn_mfma_f32_16x16x32_bf16(af, bf, acc[f], 0, 0, 0);
    }
  }

  int orow = rbase + ((lane >> 4) << 2);
  float msk[4][3];
#pragma unroll
  for (int reg = 0; reg < 4; ++reg) {
    int nd = orow + reg; if (nd > 49999) nd = 49999;
#pragma unroll
    for (int r = 0; r < 3; ++r)
      msk[reg][r] = cnt1g[nd * 4 + r] ? 1.0f : 0.0f;
  }
#pragma unroll
  for (int f = 0; f < 8; ++f) {
    int col = (f << 4) + (lane & 15);
    float bb0 = b1[col], bb1 = b1[128 + col], bb2 = b1[256 + col];
#pragma unroll
    for (int reg = 0; reg < 4; ++reg) {
      int nd = orow + reg;
      if (nd < 50000) {
        float v = acc[f][reg] + msk[reg][0] * bb0 + msk[reg][1] * bb1 + msk[reg][2] * bb2;
        v = (v >= 0.f) ? v : 0.01f * v;
        hb[(nd << 7) + col] = f2bf(v);
      }
    }
  }
}

// ---- GEMM2: Wh2[r] = h @ W2_r + b2_r, bf16 out ----
__global__ __launch_bounds__(256) void gemm2_k(
    const unsigned short* __restrict__ hb, const unsigned short* __restrict__ w2t,
    const float* __restrict__ b2, unsigned short* __restrict__ wh2) {
  int lane = threadIdx.x & 63;
  int wave = threadIdx.x >> 6;
  int rbase = blockIdx.x * 64 + wave * 16;
  int arow = rbase + (lane & 15);
  int anode = arow < 50000 ? arow : 49999;
  int kg = lane >> 4;

  const floatx4 fzero = {0.f, 0.f, 0.f, 0.f};
  floatx4 acc[12];
#pragma unroll
  for (int f = 0; f < 12; ++f) acc[f] = fzero;

#pragma unroll
  for (int ks = 0; ks < 4; ++ks) {
    int k0 = (ks << 5) + (kg << 3);
    short8 af = *(const short8*)(hb + (anode << 7) + k0);
#pragma unroll
    for (int f = 0; f < 12; ++f) {
      int col = (f << 4) + (lane & 15);
      int r = col >> 6, c0 = col & 63;
      short8 bf = *(const short8*)(w2t + (r << 13) + (c0 << 7) + k0);
      acc[f] = __builtin_amdgcn_mfma_f32_16x16x32_bf16(af, bf, acc[f], 0, 0, 0);
    }
  }
  int orow = rbase + ((lane >> 4) << 2);
#pragma unroll
  for (int f = 0; f < 12; ++f) {
    int col = (f << 4) + (lane & 15);
    int r = col >> 6, c0 = col & 63;
    float bv = b2[(r << 6) + c0];
#pragma unroll
    for (int reg = 0; reg < 4; ++reg) {
      int nd = orow + reg;
      if (nd < 50000) {
        float v = acc[f][reg] + bv;
        wh2[((r * 50000 + nd) << 6) + c0] = f2bf(v);
      }
    }
  }
}

// ---- layer-2 agg + final: one block per bucket, half-wave per edge, f32 out ----
__global__ __launch_bounds__(512) void agg2_k(
    const int* __restrict__ gbase, const unsigned* __restrict__ sorted,
    const unsigned* __restrict__ wh24, float* __restrict__ out) {
  __shared__ float acc[8192];    // [128 keys][64 slots]  slot(d) = (d>>1) + (d&1)*32
  __shared__ int cnt[128];
  int tid = threadIdx.x, lane = tid & 63, wid = tid >> 6;
  int which = lane >> 5, d2 = lane & 31;
  int b = blockIdx.x;
  for (int i = tid; i < 8192; i += 512) acc[i] = 0.f;
  if (tid < 128) cnt[tid] = 0;
  __syncthreads();
  int start = gbase[(NB + b) * NCH];
  int end = (b == NB - 1) ? 4800000 : gbase[(NB + b + 1) * NCH];
  for (int eb = start + wid * 2; eb < end; eb += 32) {  // 2 edges/wave, 2-deep unroll
    int ea = eb + which, ec = eb + 16 + which;
    unsigned va = (ea < end) ? sorted[ea] : 0u;
    unsigned vc = (ec < end) ? sorted[ec] : 0u;
    unsigned pa = 0u, pc = 0u;
    if (ea < end) pa = wh24[((((va >> 16) & 3) * 50000 + (va & 0xFFFFu)) << 5) + d2];
    if (ec < end) pc = wh24[((((vc >> 16) & 3) * 50000 + (vc & 0xFFFFu)) << 5) + d2];
    if (ea < end) {
      int l = va >> 16;
      unsafeAtomicAdd(&acc[(l << 6) + d2], __uint_as_float(pa << 16));
      unsafeAtomicAdd(&acc[(l << 6) + 32 + d2], __uint_as_float(pa & 0xFFFF0000u));
      if (d2 == 0) atomicAdd(&cnt[l], 1);
    }
    if (ec < end) {
      int l = vc >> 16;
      unsafeAtomicAdd(&acc[(l << 6) + d2], __uint_as_float(pc << 16));
      unsafeAtomicAdd(&acc[(l << 6) + 32 + d2], __uint_as_float(pc & 0xFFFF0000u));
      if (d2 == 0) atomicAdd(&cnt[l], 1);
    }
  }
  __syncthreads();
  int ln = tid >> 5, dd = tid & 31;
  for (int n = ln; n < 32; n += 16) {
    int node = (b << 5) + n;
    if (node >= 50000) break;
    float o0 = 0.f, o1 = 0.f;
#pragma unroll
    for (int r = 0; r < 3; ++r) {
      int kk = (n << 2) + r;
      float inv = 1.0f / fmaxf((float)cnt[kk], 1.0f);
      o0 += acc[(kk << 6) + dd] * inv;
      o1 += acc[(kk << 6) + 32 + dd] * inv;
    }
    float2 o; o.x = o0; o.y = o1;
    ((float2*)out)[(node << 5) + dd] = o;
  }
}

extern "C" void kernel_launch(void* const* d_in, const int* in_sizes, int n_in,
                              void* d_out, int out_size, void* d_ws, size_t ws_size,
                              hipStream_t stream) {
  const float* feat = (const float*)d_in[0];
  const float* W1   = (const float*)d_in[1];
  const float* b1   = (const float*)d_in[2];
  const float* W2   = (const float*)d_in[3];
  const float* b2   = (const float*)d_in[4];
  const int* es1 = (const int*)d_in[5];
  const int* ed1 = (const int*)d_in[6];
  const int* es2 = (const int*)d_in[7];
  const int* ed2 = (const int*)d_in[8];

  char* ws = (char*)d_ws;
  int* ghist        = (int*)(ws + 0);            // 231,324 ints
  int* blksum       = (int*)(ws + 1000192);      // 226 ints
  unsigned* sorted  = (unsigned*)(ws + 1001472); // 4.8M uints = 19.2 MB
  int* cnt1g        = (int*)(ws + 20201472);     // 200,064 ints
  unsigned short* featb = (unsigned short*)(ws + 21001728);  // 12.8 MB
  unsigned short* s1m   = (unsigned short*)(ws + 33801728);  // 38.4 MB
  unsigned short* hb    = (unsigned short*)(ws + 72201728);  // 12.8 MB
  unsigned short* wh2   = (unsigned short*)(ws + 85001728);  // 19.2 MB
  unsigned short* w1t   = (unsigned short*)(ws + 104201728); // 98,304 B
  unsigned short* w2t   = (unsigned short*)(ws + 104300032); // 49,152 B

  prep_k<<<6538, 256, 0, stream>>>(feat, W1, W2, featb, w1t, w2t);
  count_k<<<2 * NCH, 256, 0, stream>>>(ed1, ed2, ghist);
  scan1_k<<<SCAN_NBLK, 256, 0, stream>>>(ghist, blksum);
  scan2_k<<<1, 64, 0, stream>>>(blksum);
  scan3_k<<<SCAN_NBLK, 256, 0, stream>>>(ghist, blksum);
  scatter_k<<<2 * NCH, 256, 0, stream>>>(es1, ed1, es2, ed2, ghist, sorted);
  agg1_k<<<NB, 512, 0, stream>>>(ghist, sorted, (const unsigned*)featb,
                                 (unsigned*)s1m, cnt1g);
  gemm1_k<<<782, 256, 0, stream>>>(s1m, cnt1g, w1t, b1, hb);
  gemm2_k<<<782, 256, 0, stream>>>(hb, w2t, b2, wh2);
  agg2_k<<<NB, 512, 0, stream>>>(ghist, sorted, (const unsigned*)wh2, (float*)d_out);
}

// Round 4
// 529.481 us; speedup vs baseline: 5.7690x; 5.7690x over previous
//
#include <hip/hip_runtime.h>

typedef __attribute__((ext_vector_type(8))) short short8;
typedef __attribute__((ext_vector_type(4))) float floatx4;

#define NCH 147         // chunks per layer
#define CH 16384        // edges per chunk
#define NB 1563         // coarse buckets (128 keys each)
#define NKP 200064      // padded key count (NB*128)
#define SCAN_T (2 * NB * NCH)
#define SCAN_NBLK 449   // ceil(SCAN_T/1024)

__device__ __forceinline__ unsigned short f2bf(float f) {
  unsigned u = __float_as_uint(f);
  u += 0x7FFFu + ((u >> 16) & 1u);
  return (unsigned short)(u >> 16);
}
__device__ __forceinline__ float bf2f(unsigned short b) {
  return __uint_as_float(((unsigned)b) << 16);
}

// ---- prep: feat->bf16; W1 -> W1T [3][n=128][k=128]; W2 -> W2T [3][n=64][k=128] ----
__global__ __launch_bounds__(256) void prep_k(
    const float* __restrict__ feat, const float* __restrict__ W1,
    const float* __restrict__ W2, unsigned short* __restrict__ featb,
    unsigned short* __restrict__ w1t, unsigned short* __restrict__ w2t) {
  int tid = blockIdx.x * 256 + threadIdx.x;
  if (tid < 1600000) {
    float4 v = ((const float4*)feat)[tid];
    ushort4 o;
    o.x = f2bf(v.x); o.y = f2bf(v.y); o.z = f2bf(v.z); o.w = f2bf(v.w);
    ((ushort4*)featb)[tid] = o;
  } else if (tid < 1600000 + 49152) {
    int t = tid - 1600000;
    int r = t >> 14, rem = t & 16383, n = rem >> 7, k = rem & 127;
    w1t[t] = f2bf(W1[(r << 14) + (k << 7) + n]);
  } else if (tid < 1600000 + 49152 + 24576) {
    int t = tid - 1649152;
    int r = t >> 13, rem = t & 8191, n = rem >> 7, k = rem & 127;
    w2t[t] = f2bf(W2[(r << 13) + (k << 6) + n]);
  }
}

// ---- pass A: per-chunk bucket histograms -> ghist[layer][b][c] ----
__global__ __launch_bounds__(256) void count_k(
    const int* __restrict__ ed1, const int* __restrict__ ed2,
    int* __restrict__ ghist) {
  __shared__ int h[NB];
  int tid = threadIdx.x;
  int layer = blockIdx.x >= NCH;
  int c = blockIdx.x - layer * NCH;
  const int* ed = layer ? ed2 : ed1;
  for (int i = tid; i < NB; i += 256) h[i] = 0;
  __syncthreads();
  int j0 = c * CH;
  for (int it = 0; it < CH / 256; ++it) {
    int j = j0 + it * 256 + tid;
    if (j < 2400000) {
      int key = ed[j] * 4 + j / 800000;
      atomicAdd(&h[key >> 7], 1);
    }
  }
  __syncthreads();
  int base = layer * NB * NCH;
  for (int b = tid; b < NB; b += 256) ghist[base + b * NCH + c] = h[b];
}

// ---- scan: 3-phase exclusive prefix over ghist (in place) ----
__global__ __launch_bounds__(256) void scan1_k(const int* __restrict__ g,
                                               int* __restrict__ blksum) {
  __shared__ int ws_[4];
  int tid = threadIdx.x;
  int base = blockIdx.x * 1024 + tid * 4;
  int s = 0;
#pragma unroll
  for (int k = 0; k < 4; ++k) { int i = base + k; if (i < SCAN_T) s += g[i]; }
#pragma unroll
  for (int o = 32; o > 0; o >>= 1) s += __shfl_down(s, o);
  if ((tid & 63) == 0) ws_[tid >> 6] = s;
  __syncthreads();
  if (tid == 0) blksum[blockIdx.x] = ws_[0] + ws_[1] + ws_[2] + ws_[3];
}
__global__ __launch_bounds__(64) void scan2_k(int* __restrict__ blksum) {
  int lane = threadIdx.x;
  int carry = 0;
  for (int g0 = 0; g0 < SCAN_NBLK; g0 += 64) {
    int i = g0 + lane;
    int v = (i < SCAN_NBLK) ? blksum[i] : 0;
    int inc = v;
#pragma unroll
    for (int o = 1; o < 64; o <<= 1) { int u = __shfl_up(inc, o); if (lane >= o) inc += u; }
    if (i < SCAN_NBLK) blksum[i] = carry + inc - v;
    carry += __shfl(inc, 63);
  }
}
__global__ __launch_bounds__(256) void scan3_k(int* __restrict__ g,
                                               const int* __restrict__ blksum) {
  __shared__ int wt[4];
  int tid = threadIdx.x, lane = tid & 63, w = tid >> 6;
  int base = blockIdx.x * 1024 + tid * 4;
  int v[4]; int s = 0;
#pragma unroll
  for (int k = 0; k < 4; ++k) { int i = base + k; v[k] = (i < SCAN_T) ? g[i] : 0; s += v[k]; }
  int inc = s;
#pragma unroll
  for (int o = 1; o < 64; o <<= 1) { int u = __shfl_up(inc, o); if (lane >= o) inc += u; }
  if (lane == 63) wt[w] = inc;
  __syncthreads();
  int woff = 0;
#pragma unroll
  for (int k = 0; k < 4; ++k) if (k < w) woff += wt[k];
  int excl = blksum[blockIdx.x] + woff + inc - s;
#pragma unroll
  for (int k = 0; k < 4; ++k) {
    int i = base + k;
    if (i < SCAN_T) g[i] = excl;
    excl += v[k];
  }
}

// ---- pass B: chunk-local LDS-cursor scatter -> sorted[] (src | within-bucket-key<<16) ----
__global__ __launch_bounds__(256) void scatter_k(
    const int* __restrict__ es1, const int* __restrict__ ed1,
    const int* __restrict__ es2, const int* __restrict__ ed2,
    const int* __restrict__ gbase, unsigned* __restrict__ sorted) {
  __shared__ int cur[NB];
  int tid = threadIdx.x;
  int layer = blockIdx.x >= NCH;
  int c = blockIdx.x - layer * NCH;
  const int* es = layer ? es2 : es1;
  const int* ed = layer ? ed2 : ed1;
  int gb = layer * NB * NCH;
  for (int b = tid; b < NB; b += 256) cur[b] = gbase[gb + b * NCH + c];
  __syncthreads();
  int j0 = c * CH;
  for (int it = 0; it < CH / 256; ++it) {
    int j = j0 + it * 256 + tid;
    if (j < 2400000) {
      int key = ed[j] * 4 + j / 800000;
      int pos = atomicAdd(&cur[key >> 7], 1);
      sorted[pos] = (unsigned)es[j] | ((unsigned)(key & 127) << 16);
    }
  }
}

// ---- per-bucket micro-sort: bucket-grouped -> key-sorted ushort srcs + off/cnt ----
__global__ __launch_bounds__(256) void sortb_k(
    const int* __restrict__ gbase, const unsigned* __restrict__ sorted,
    unsigned short* __restrict__ sorted2, int* __restrict__ offk,
    int* __restrict__ cntk) {
  __shared__ int hist[128], cur[128];
  int tid = threadIdx.x;
  int layer = blockIdx.x >= NB;
  int b = blockIdx.x - layer * NB;
  int start = gbase[(layer * NB + b) * NCH];
  int end = (layer == 1 && b == NB - 1) ? 4800000
                                        : gbase[(layer * NB + b + 1) * NCH];
  if (tid < 128) hist[tid] = 0;
  __syncthreads();
  for (int e = start + tid; e < end; e += 256)
    atomicAdd(&hist[sorted[e] >> 16], 1);
  __syncthreads();
  if (tid < 64) {
    int lane = tid;
    int h0 = hist[lane], h1 = hist[64 + lane];
    int i0 = h0, i1 = h1;
#pragma unroll
    for (int o = 1; o < 64; o <<= 1) {
      int u0 = __shfl_up(i0, o), u1 = __shfl_up(i1, o);
      if (lane >= o) { i0 += u0; i1 += u1; }
    }
    int t0 = __shfl(i0, 63);
    int e0 = i0 - h0, e1 = t0 + i1 - h1;
    cur[lane] = e0; cur[64 + lane] = e1;
    int lb = layer * NKP + (b << 7) + lane;
    offk[lb] = start + e0; cntk[lb] = h0;
    offk[lb + 64] = start + e1; cntk[lb + 64] = h1;
  }
  __syncthreads();
  for (int e = start + tid; e < end; e += 256) {
    unsigned v = sorted[e];
    int p = atomicAdd(&cur[v >> 16], 1);
    sorted2[start + p] = (unsigned short)(v & 0xFFFFu);
  }
}

// ---- layer-1 agg: wave per node, 8-deep gather, write mean as bf16 ----
__global__ __launch_bounds__(256) void agg1_k(
    const int* __restrict__ offk, const int* __restrict__ cntk,
    const unsigned short* __restrict__ sorted2,
    const unsigned* __restrict__ featb4, unsigned* __restrict__ s1m4) {
  int lane = threadIdx.x & 63;
  int v = blockIdx.x * 4 + (threadIdx.x >> 6);
  if (v >= 50000) return;
  const unsigned* fb = featb4 + lane;
#pragma unroll
  for (int r = 0; r < 3; ++r) {
    int key = v * 4 + r;
    int base = offk[key], n = cntk[key];
    float a0 = 0.f, a1 = 0.f;
    for (int jb = 0; jb < n; jb += 64) {
      int m = n - jb; if (m > 64) m = 64;
      int my = (lane < m) ? (int)sorted2[base + jb + lane] : 0;
      int k = 0;
      for (; k + 8 <= m; k += 8) {
        int s0 = __shfl(my, k),     s1 = __shfl(my, k + 1);
        int s2 = __shfl(my, k + 2), s3 = __shfl(my, k + 3);
        int s4 = __shfl(my, k + 4), s5 = __shfl(my, k + 5);
        int s6 = __shfl(my, k + 6), s7 = __shfl(my, k + 7);
        unsigned p0 = fb[s0 << 6], p1 = fb[s1 << 6];
        unsigned p2 = fb[s2 << 6], p3 = fb[s3 << 6];
        unsigned p4 = fb[s4 << 6], p5 = fb[s5 << 6];
        unsigned p6 = fb[s6 << 6], p7 = fb[s7 << 6];
        a0 += __uint_as_float(p0 << 16) + __uint_as_float(p1 << 16) +
              __uint_as_float(p2 << 16) + __uint_as_float(p3 << 16) +
              __uint_as_float(p4 << 16) + __uint_as_float(p5 << 16) +
              __uint_as_float(p6 << 16) + __uint_as_float(p7 << 16);
        a1 += __uint_as_float(p0 & 0xFFFF0000u) + __uint_as_float(p1 & 0xFFFF0000u) +
              __uint_as_float(p2 & 0xFFFF0000u) + __uint_as_float(p3 & 0xFFFF0000u) +
              __uint_as_float(p4 & 0xFFFF0000u) + __uint_as_float(p5 & 0xFFFF0000u) +
              __uint_as_float(p6 & 0xFFFF0000u) + __uint_as_float(p7 & 0xFFFF0000u);
      }
      for (; k < m; ++k) {
        int s = __shfl(my, k);
        unsigned p = fb[s << 6];
        a0 += __uint_as_float(p << 16);
        a1 += __uint_as_float(p & 0xFFFF0000u);
      }
    }
    float inv = 1.0f / fmaxf((float)n, 1.0f);
    unsigned pk = ((unsigned)f2bf(a1 * inv) << 16) | (unsigned)f2bf(a0 * inv);
    s1m4[(r * 50000 + v) * 64 + lane] = pk;
  }
}

// ---- GEMM1: h = leaky( sum_r s1m_r @ W1_r + b1_r*[cnt>0] ), bf16 out ----
__global__ __launch_bounds__(256) void gemm1_k(
    const unsigned short* __restrict__ s1m, const int* __restrict__ cntk,
    const unsigned short* __restrict__ w1t, const float* __restrict__ b1,
    unsigned short* __restrict__ hb) {
  int lane = threadIdx.x & 63;
  int wave = threadIdx.x >> 6;
  int rbase = blockIdx.x * 64 + wave * 16;
  int arow = rbase + (lane & 15);
  int anode = arow < 50000 ? arow : 49999;
  int kg = lane >> 4;

  const floatx4 fzero = {0.f, 0.f, 0.f, 0.f};
  floatx4 acc[8];
#pragma unroll
  for (int f = 0; f < 8; ++f) acc[f] = fzero;

#pragma unroll
  for (int ks = 0; ks < 12; ++ks) {
    int r = ks >> 2;
    int k0 = ((ks & 3) << 5) + (kg << 3);
    short8 af = *(const short8*)(s1m + ((r * 50000 + anode) << 7) + k0);
#pragma unroll
    for (int f = 0; f < 8; ++f) {
      int n = (f << 4) + (lane & 15);
      short8 bf = *(const short8*)(w1t + (r << 14) + (n << 7) + k0);
      acc[f] = __builtin_amdgcn_mfma_f32_16x16x32_bf16(af, bf, acc[f], 0, 0, 0);
    }
  }

  int orow = rbase + ((lane >> 4) << 2);
  float msk[4][3];
#pragma unroll
  for (int reg = 0; reg < 4; ++reg) {
    int nd = orow + reg; if (nd > 49999) nd = 49999;
#pragma unroll
    for (int r = 0; r < 3; ++r)
      msk[reg][r] = cntk[nd * 4 + r] ? 1.0f : 0.0f;
  }
#pragma unroll
  for (int f = 0; f < 8; ++f) {
    int col = (f << 4) + (lane & 15);
    float bb0 = b1[col], bb1 = b1[128 + col], bb2 = b1[256 + col];
#pragma unroll
    for (int reg = 0; reg < 4; ++reg) {
      int nd = orow + reg;
      if (nd < 50000) {
        float v = acc[f][reg] + msk[reg][0] * bb0 + msk[reg][1] * bb1 + msk[reg][2] * bb2;
        v = (v >= 0.f) ? v : 0.01f * v;
        hb[(nd << 7) + col] = f2bf(v);
      }
    }
  }
}

// ---- GEMM2: Wh2[r] = h @ W2_r + b2_r, bf16 out ----
__global__ __launch_bounds__(256) void gemm2_k(
    const unsigned short* __restrict__ hb, const unsigned short* __restrict__ w2t,
    const float* __restrict__ b2, unsigned short* __restrict__ wh2) {
  int lane = threadIdx.x & 63;
  int wave = threadIdx.x >> 6;
  int rbase = blockIdx.x * 64 + wave * 16;
  int arow = rbase + (lane & 15);
  int anode = arow < 50000 ? arow : 49999;
  int kg = lane >> 4;

  const floatx4 fzero = {0.f, 0.f, 0.f, 0.f};
  floatx4 acc[12];
#pragma unroll
  for (int f = 0; f < 12; ++f) acc[f] = fzero;

#pragma unroll
  for (int ks = 0; ks < 4; ++ks) {
    int k0 = (ks << 5) + (kg << 3);
    short8 af = *(const short8*)(hb + (anode << 7) + k0);
#pragma unroll
    for (int f = 0; f < 12; ++f) {
      int col = (f << 4) + (lane & 15);
      int r = col >> 6, c0 = col & 63;
      short8 bf = *(const short8*)(w2t + (r << 13) + (c0 << 7) + k0);
      acc[f] = __builtin_amdgcn_mfma_f32_16x16x32_bf16(af, bf, acc[f], 0, 0, 0);
    }
  }
  int orow = rbase + ((lane >> 4) << 2);
#pragma unroll
  for (int f = 0; f < 12; ++f) {
    int col = (f << 4) + (lane & 15);
    int r = col >> 6, c0 = col & 63;
    float bv = b2[(r << 6) + c0];
#pragma unroll
    for (int reg = 0; reg < 4; ++reg) {
      int nd = orow + reg;
      if (nd < 50000) {
        float v = acc[f][reg] + bv;
        wh2[((r * 50000 + nd) << 6) + c0] = f2bf(v);
      }
    }
  }
}

// ---- layer-2 agg + final: wave per node, 8-deep gather, f32 out ----
__global__ __launch_bounds__(256) void agg2f_k(
    const int* __restrict__ offk, const int* __restrict__ cntk,
    const unsigned short* __restrict__ sorted2,
    const unsigned short* __restrict__ wh2, float* __restrict__ out) {
  int lane = threadIdx.x & 63;
  int v = blockIdx.x * 4 + (threadIdx.x >> 6);
  if (v >= 50000) return;
  float o = 0.f;
#pragma unroll
  for (int r = 0; r < 3; ++r) {
    int key = NKP + v * 4 + r;
    int base = offk[key], n = cntk[key];
    const unsigned short* wb = wh2 + ((long)r * 50000 << 6) + lane;
    float a = 0.f;
    for (int jb = 0; jb < n; jb += 64) {
      int m = n - jb; if (m > 64) m = 64;
      int my = (lane < m) ? (int)sorted2[base + jb + lane] : 0;
      int k = 0;
      for (; k + 8 <= m; k += 8) {
        int s0 = __shfl(my, k),     s1 = __shfl(my, k + 1);
        int s2 = __shfl(my, k + 2), s3 = __shfl(my, k + 3);
        int s4 = __shfl(my, k + 4), s5 = __shfl(my, k + 5);
        int s6 = __shfl(my, k + 6), s7 = __shfl(my, k + 7);
        a += bf2f(wb[s0 << 6]) + bf2f(wb[s1 << 6]) +
             bf2f(wb[s2 << 6]) + bf2f(wb[s3 << 6]) +
             bf2f(wb[s4 << 6]) + bf2f(wb[s5 << 6]) +
             bf2f(wb[s6 << 6]) + bf2f(wb[s7 << 6]);
      }
      for (; k < m; ++k) a += bf2f(wb[__shfl(my, k) << 6]);
    }
    o += a / fmaxf((float)n, 1.0f);
  }
  out[(v << 6) + lane] = o;
}

extern "C" void kernel_launch(void* const* d_in, const int* in_sizes, int n_in,
                              void* d_out, int out_size, void* d_ws, size_t ws_size,
                              hipStream_t stream) {
  const float* feat = (const float*)d_in[0];
  const float* W1   = (const float*)d_in[1];
  const float* b1   = (const float*)d_in[2];
  const float* W2   = (const float*)d_in[3];
  const float* b2   = (const float*)d_in[4];
  const int* es1 = (const int*)d_in[5];
  const int* ed1 = (const int*)d_in[6];
  const int* es2 = (const int*)d_in[7];
  const int* ed2 = (const int*)d_in[8];

  char* ws = (char*)d_ws;
  int* ghist           = (int*)(ws + 0);            // 459,522 ints = 1,838,088 B
  int* blksum          = (int*)(ws + 1840000);      // 449 ints
  unsigned* sorted     = (unsigned*)(ws + 1848192); // 19.2 MB
  unsigned short* sorted2 = (unsigned short*)(ws + 21048192); // 9.6 MB
  int* offk            = (int*)(ws + 30648192);     // 2*200064 ints = 1,600,512 B
  int* cntk            = (int*)(ws + 32248704);     // 1,600,512 B
  unsigned short* featb = (unsigned short*)(ws + 33849216);  // 12.8 MB
  unsigned short* s1m   = (unsigned short*)(ws + 46649216);  // 38.4 MB
  unsigned short* hb    = (unsigned short*)(ws + 85049216);  // 12.8 MB
  unsigned short* wh2   = (unsigned short*)(ws + 97849216);  // 19.2 MB
  unsigned short* w1t   = (unsigned short*)(ws + 117049216); // 98,304 B
  unsigned short* w2t   = (unsigned short*)(ws + 117147520); // 49,152 B

  prep_k<<<6538, 256, 0, stream>>>(feat, W1, W2, featb, w1t, w2t);
  count_k<<<2 * NCH, 256, 0, stream>>>(ed1, ed2, ghist);
  scan1_k<<<SCAN_NBLK, 256, 0, stream>>>(ghist, blksum);
  scan2_k<<<1, 64, 0, stream>>>(blksum);
  scan3_k<<<SCAN_NBLK, 256, 0, stream>>>(ghist, blksum);
  scatter_k<<<2 * NCH, 256, 0, stream>>>(es1, ed1, es2, ed2, ghist, sorted);
  sortb_k<<<2 * NB, 256, 0, stream>>>(ghist, sorted, sorted2, offk, cntk);
  agg1_k<<<12500, 256, 0, stream>>>(offk, cntk, sorted2, (const unsigned*)featb,
                                    (unsigned*)s1m);
  gemm1_k<<<782, 256, 0, stream>>>(s1m, cntk, w1t, b1, hb);
  gemm2_k<<<782, 256, 0, stream>>>(hb, w2t, b2, wh2);
  agg2f_k<<<12500, 256, 0, stream>>>(offk, cntk, sorted2, wh2, (float*)d_out);
}

// Round 5
// 466.672 us; speedup vs baseline: 6.5455x; 1.1346x over previous
//
#include <hip/hip_runtime.h>

typedef __attribute__((ext_vector_type(8))) short short8;
typedef __attribute__((ext_vector_type(4))) float floatx4;

#define NCH 147         // chunks per layer
#define CH 16384        // edges per chunk
#define NB 391          // coarse buckets (512 keys each)
#define NKP 200192      // padded key count (NB*512)
#define SCAN_T (2 * NB * NCH)   // 114954
#define SCAN_NBLK 113   // ceil(SCAN_T/1024)

__device__ __forceinline__ unsigned short f2bf(float f) {
  unsigned u = __float_as_uint(f);
  u += 0x7FFFu + ((u >> 16) & 1u);
  return (unsigned short)(u >> 16);
}
__device__ __forceinline__ float bf2f(unsigned short b) {
  return __uint_as_float(((unsigned)b) << 16);
}

// ---- prep: feat->bf16; W1 -> W1T [3][n=128][k=128]; W2 -> W2T [3][n=64][k=128] ----
__global__ __launch_bounds__(256) void prep_k(
    const float* __restrict__ feat, const float* __restrict__ W1,
    const float* __restrict__ W2, unsigned short* __restrict__ featb,
    unsigned short* __restrict__ w1t, unsigned short* __restrict__ w2t) {
  int tid = blockIdx.x * 256 + threadIdx.x;
  if (tid < 1600000) {
    float4 v = ((const float4*)feat)[tid];
    ushort4 o;
    o.x = f2bf(v.x); o.y = f2bf(v.y); o.z = f2bf(v.z); o.w = f2bf(v.w);
    ((ushort4*)featb)[tid] = o;
  } else if (tid < 1600000 + 49152) {
    int t = tid - 1600000;
    int r = t >> 14, rem = t & 16383, n = rem >> 7, k = rem & 127;
    w1t[t] = f2bf(W1[(r << 14) + (k << 7) + n]);
  } else if (tid < 1600000 + 49152 + 24576) {
    int t = tid - 1649152;
    int r = t >> 13, rem = t & 8191, n = rem >> 7, k = rem & 127;
    w2t[t] = f2bf(W2[(r << 13) + (k << 6) + n]);
  }
}

// ---- pass A: per-chunk bucket histograms -> ghist[layer][b][c] ----
__global__ __launch_bounds__(1024) void count_k(
    const int* __restrict__ ed1, const int* __restrict__ ed2,
    int* __restrict__ ghist) {
  __shared__ int h[NB];
  int tid = threadIdx.x;
  int layer = blockIdx.x >= NCH;
  int c = blockIdx.x - layer * NCH;
  const int* ed = layer ? ed2 : ed1;
  if (tid < NB) h[tid] = 0;
  __syncthreads();
  int j0 = c * CH;
  for (int it = 0; it < CH / 1024; ++it) {
    int j = j0 + it * 1024 + tid;
    if (j < 2400000) {
      int key = ed[j] * 4 + j / 800000;
      atomicAdd(&h[key >> 9], 1);
    }
  }
  __syncthreads();
  int base = layer * NB * NCH;
  if (tid < NB) ghist[base + tid * NCH + c] = h[tid];
}

// ---- scan: 3-phase exclusive prefix over ghist (in place) ----
__global__ __launch_bounds__(256) void scan1_k(const int* __restrict__ g,
                                               int* __restrict__ blksum) {
  __shared__ int ws_[4];
  int tid = threadIdx.x;
  int base = blockIdx.x * 1024 + tid * 4;
  int s = 0;
#pragma unroll
  for (int k = 0; k < 4; ++k) { int i = base + k; if (i < SCAN_T) s += g[i]; }
#pragma unroll
  for (int o = 32; o > 0; o >>= 1) s += __shfl_down(s, o);
  if ((tid & 63) == 0) ws_[tid >> 6] = s;
  __syncthreads();
  if (tid == 0) blksum[blockIdx.x] = ws_[0] + ws_[1] + ws_[2] + ws_[3];
}
__global__ __launch_bounds__(64) void scan2_k(int* __restrict__ blksum) {
  int lane = threadIdx.x;
  int carry = 0;
  for (int g0 = 0; g0 < SCAN_NBLK; g0 += 64) {
    int i = g0 + lane;
    int v = (i < SCAN_NBLK) ? blksum[i] : 0;
    int inc = v;
#pragma unroll
    for (int o = 1; o < 64; o <<= 1) { int u = __shfl_up(inc, o); if (lane >= o) inc += u; }
    if (i < SCAN_NBLK) blksum[i] = carry + inc - v;
    carry += __shfl(inc, 63);
  }
}
__global__ __launch_bounds__(256) void scan3_k(int* __restrict__ g,
                                               const int* __restrict__ blksum) {
  __shared__ int wt[4];
  int tid = threadIdx.x, lane = tid & 63, w = tid >> 6;
  int base = blockIdx.x * 1024 + tid * 4;
  int v[4]; int s = 0;
#pragma unroll
  for (int k = 0; k < 4; ++k) { int i = base + k; v[k] = (i < SCAN_T) ? g[i] : 0; s += v[k]; }
  int inc = s;
#pragma unroll
  for (int o = 1; o < 64; o <<= 1) { int u = __shfl_up(inc, o); if (lane >= o) inc += u; }
  if (lane == 63) wt[w] = inc;
  __syncthreads();
  int woff = 0;
#pragma unroll
  for (int k = 0; k < 4; ++k) if (k < w) woff += wt[k];
  int excl = blksum[blockIdx.x] + woff + inc - s;
#pragma unroll
  for (int k = 0; k < 4; ++k) {
    int i = base + k;
    if (i < SCAN_T) g[i] = excl;
    excl += v[k];
  }
}

// ---- pass B: chunk-local LDS-cursor scatter -> sorted[] (src | within-bucket-key<<16) ----
__global__ __launch_bounds__(1024) void scatter_k(
    const int* __restrict__ es1, const int* __restrict__ ed1,
    const int* __restrict__ es2, const int* __restrict__ ed2,
    const int* __restrict__ gbase, unsigned* __restrict__ sorted) {
  __shared__ int cur[NB];
  int tid = threadIdx.x;
  int layer = blockIdx.x >= NCH;
  int c = blockIdx.x - layer * NCH;
  const int* es = layer ? es2 : es1;
  const int* ed = layer ? ed2 : ed1;
  int gb = layer * NB * NCH;
  if (tid < NB) cur[tid] = gbase[gb + tid * NCH + c];
  __syncthreads();
  int j0 = c * CH;
  for (int it = 0; it < CH / 1024; ++it) {
    int j = j0 + it * 1024 + tid;
    if (j < 2400000) {
      int key = ed[j] * 4 + j / 800000;
      int pos = atomicAdd(&cur[key >> 9], 1);
      sorted[pos] = (unsigned)es[j] | ((unsigned)(key & 511) << 16);
    }
  }
}

// ---- per-bucket micro-sort: bucket-grouped -> key-sorted ushort srcs + off/cnt ----
__global__ __launch_bounds__(512) void sortb_k(
    const int* __restrict__ gbase, const unsigned* __restrict__ sorted,
    unsigned short* __restrict__ sorted2, int* __restrict__ offk,
    int* __restrict__ cntk) {
  __shared__ int hist[512], cur[512];
  int tid = threadIdx.x;
  int layer = blockIdx.x >= NB;
  int b = blockIdx.x - layer * NB;
  int start = gbase[(layer * NB + b) * NCH];
  int end = (layer == 1 && b == NB - 1) ? 4800000
                                        : gbase[(layer * NB + b + 1) * NCH];
  hist[tid] = 0;
  __syncthreads();
  for (int e = start + tid; e < end; e += 512)
    atomicAdd(&hist[sorted[e] >> 16], 1);
  __syncthreads();
  if (tid < 64) {
    int carry = 0;
    for (int g0 = 0; g0 < 512; g0 += 64) {
      int h = hist[g0 + tid];
      int inc = h;
#pragma unroll
      for (int o = 1; o < 64; o <<= 1) {
        int u = __shfl_up(inc, o);
        if (tid >= o) inc += u;
      }
      int excl = carry + inc - h;
      cur[g0 + tid] = excl;
      int lb = layer * NKP + (b << 9) + g0 + tid;
      offk[lb] = start + excl;
      cntk[lb] = h;
      carry += __shfl(inc, 63);
    }
  }
  __syncthreads();
  for (int e = start + tid; e < end; e += 512) {
    unsigned v = sorted[e];
    int p = atomicAdd(&cur[v >> 16], 1);
    sorted2[start + p] = (unsigned short)(v & 0xFFFFu);
  }
}

// ---- layer-1 agg: wave per node, 8-deep gather, write mean as bf16 ----
__global__ __launch_bounds__(256) void agg1_k(
    const int* __restrict__ offk, const int* __restrict__ cntk,
    const unsigned short* __restrict__ sorted2,
    const unsigned* __restrict__ featb4, unsigned* __restrict__ s1m4) {
  int lane = threadIdx.x & 63;
  int v = blockIdx.x * 4 + (threadIdx.x >> 6);
  if (v >= 50000) return;
  const unsigned* fb = featb4 + lane;
#pragma unroll
  for (int r = 0; r < 3; ++r) {
    int key = v * 4 + r;
    int base = offk[key], n = cntk[key];
    float a0 = 0.f, a1 = 0.f;
    for (int jb = 0; jb < n; jb += 64) {
      int m = n - jb; if (m > 64) m = 64;
      int my = (lane < m) ? (int)sorted2[base + jb + lane] : 0;
      int k = 0;
      for (; k + 8 <= m; k += 8) {
        int s0 = __shfl(my, k),     s1 = __shfl(my, k + 1);
        int s2 = __shfl(my, k + 2), s3 = __shfl(my, k + 3);
        int s4 = __shfl(my, k + 4), s5 = __shfl(my, k + 5);
        int s6 = __shfl(my, k + 6), s7 = __shfl(my, k + 7);
        unsigned p0 = fb[s0 << 6], p1 = fb[s1 << 6];
        unsigned p2 = fb[s2 << 6], p3 = fb[s3 << 6];
        unsigned p4 = fb[s4 << 6], p5 = fb[s5 << 6];
        unsigned p6 = fb[s6 << 6], p7 = fb[s7 << 6];
        a0 += __uint_as_float(p0 << 16) + __uint_as_float(p1 << 16) +
              __uint_as_float(p2 << 16) + __uint_as_float(p3 << 16) +
              __uint_as_float(p4 << 16) + __uint_as_float(p5 << 16) +
              __uint_as_float(p6 << 16) + __uint_as_float(p7 << 16);
        a1 += __uint_as_float(p0 & 0xFFFF0000u) + __uint_as_float(p1 & 0xFFFF0000u) +
              __uint_as_float(p2 & 0xFFFF0000u) + __uint_as_float(p3 & 0xFFFF0000u) +
              __uint_as_float(p4 & 0xFFFF0000u) + __uint_as_float(p5 & 0xFFFF0000u) +
              __uint_as_float(p6 & 0xFFFF0000u) + __uint_as_float(p7 & 0xFFFF0000u);
      }
      for (; k < m; ++k) {
        int s = __shfl(my, k);
        unsigned p = fb[s << 6];
        a0 += __uint_as_float(p << 16);
        a1 += __uint_as_float(p & 0xFFFF0000u);
      }
    }
    float inv = 1.0f / fmaxf((float)n, 1.0f);
    unsigned pk = ((unsigned)f2bf(a1 * inv) << 16) | (unsigned)f2bf(a0 * inv);
    s1m4[(r * 50000 + v) * 64 + lane] = pk;
  }
}

// ---- GEMM1: h = leaky( sum_r s1m_r @ W1_r + b1_r*[cnt>0] ), bf16 out ----
__global__ __launch_bounds__(256) void gemm1_k(
    const unsigned short* __restrict__ s1m, const int* __restrict__ cntk,
    const unsigned short* __restrict__ w1t, const float* __restrict__ b1,
    unsigned short* __restrict__ hb) {
  int lane = threadIdx.x & 63;
  int wave = threadIdx.x >> 6;
  int rbase = blockIdx.x * 64 + wave * 16;
  int arow = rbase + (lane & 15);
  int anode = arow < 50000 ? arow : 49999;
  int kg = lane >> 4;

  const floatx4 fzero = {0.f, 0.f, 0.f, 0.f};
  floatx4 acc[8];
#pragma unroll
  for (int f = 0; f < 8; ++f) acc[f] = fzero;

#pragma unroll
  for (int ks = 0; ks < 12; ++ks) {
    int r = ks >> 2;
    int k0 = ((ks & 3) << 5) + (kg << 3);
    short8 af = *(const short8*)(s1m + ((r * 50000 + anode) << 7) + k0);
#pragma unroll
    for (int f = 0; f < 8; ++f) {
      int n = (f << 4) + (lane & 15);
      short8 bf = *(const short8*)(w1t + (r << 14) + (n << 7) + k0);
      acc[f] = __builtin_amdgcn_mfma_f32_16x16x32_bf16(af, bf, acc[f], 0, 0, 0);
    }
  }

  int orow = rbase + ((lane >> 4) << 2);
  float msk[4][3];
#pragma unroll
  for (int reg = 0; reg < 4; ++reg) {
    int nd = orow + reg; if (nd > 49999) nd = 49999;
#pragma unroll
    for (int r = 0; r < 3; ++r)
      msk[reg][r] = cntk[nd * 4 + r] ? 1.0f : 0.0f;
  }
#pragma unroll
  for (int f = 0; f < 8; ++f) {
    int col = (f << 4) + (lane & 15);
    float bb0 = b1[col], bb1 = b1[128 + col], bb2 = b1[256 + col];
#pragma unroll
    for (int reg = 0; reg < 4; ++reg) {
      int nd = orow + reg;
      if (nd < 50000) {
        float v = acc[f][reg] + msk[reg][0] * bb0 + msk[reg][1] * bb1 + msk[reg][2] * bb2;
        v = (v >= 0.f) ? v : 0.01f * v;
        hb[(nd << 7) + col] = f2bf(v);
      }
    }
  }
}

// ---- GEMM2: Wh2[r] = h @ W2_r + b2_r, bf16 out ----
__global__ __launch_bounds__(256) void gemm2_k(
    const unsigned short* __restrict__ hb, const unsigned short* __restrict__ w2t,
    const float* __restrict__ b2, unsigned short* __restrict__ wh2) {
  int lane = threadIdx.x & 63;
  int wave = threadIdx.x >> 6;
  int rbase = blockIdx.x * 64 + wave * 16;
  int arow = rbase + (lane & 15);
  int anode = arow < 50000 ? arow : 49999;
  int kg = lane >> 4;

  const floatx4 fzero = {0.f, 0.f, 0.f, 0.f};
  floatx4 acc[12];
#pragma unroll
  for (int f = 0; f < 12; ++f) acc[f] = fzero;

#pragma unroll
  for (int ks = 0; ks < 4; ++ks) {
    int k0 = (ks << 5) + (kg << 3);
    short8 af = *(const short8*)(hb + (anode << 7) + k0);
#pragma unroll
    for (int f = 0; f < 12; ++f) {
      int col = (f << 4) + (lane & 15);
      int r = col >> 6, c0 = col & 63;
      short8 bf = *(const short8*)(w2t + (r << 13) + (c0 << 7) + k0);
      acc[f] = __builtin_amdgcn_mfma_f32_16x16x32_bf16(af, bf, acc[f], 0, 0, 0);
    }
  }
  int orow = rbase + ((lane >> 4) << 2);
#pragma unroll
  for (int f = 0; f < 12; ++f) {
    int col = (f << 4) + (lane & 15);
    int r = col >> 6, c0 = col & 63;
    float bv = b2[(r << 6) + c0];
#pragma unroll
    for (int reg = 0; reg < 4; ++reg) {
      int nd = orow + reg;
      if (nd < 50000) {
        float v = acc[f][reg] + bv;
        wh2[((r * 50000 + nd) << 6) + c0] = f2bf(v);
      }
    }
  }
}

// ---- layer-2 agg + final: wave per node, 8-deep gather, f32 out ----
__global__ __launch_bounds__(256) void agg2f_k(
    const int* __restrict__ offk, const int* __restrict__ cntk,
    const unsigned short* __restrict__ sorted2,
    const unsigned short* __restrict__ wh2, float* __restrict__ out) {
  int lane = threadIdx.x & 63;
  int v = blockIdx.x * 4 + (threadIdx.x >> 6);
  if (v >= 50000) return;
  float o = 0.f;
#pragma unroll
  for (int r = 0; r < 3; ++r) {
    int key = NKP + v * 4 + r;
    int base = offk[key], n = cntk[key];
    const unsigned short* wb = wh2 + ((long)r * 50000 << 6) + lane;
    float a = 0.f;
    for (int jb = 0; jb < n; jb += 64) {
      int m = n - jb; if (m > 64) m = 64;
      int my = (lane < m) ? (int)sorted2[base + jb + lane] : 0;
      int k = 0;
      for (; k + 8 <= m; k += 8) {
        int s0 = __shfl(my, k),     s1 = __shfl(my, k + 1);
        int s2 = __shfl(my, k + 2), s3 = __shfl(my, k + 3);
        int s4 = __shfl(my, k + 4), s5 = __shfl(my, k + 5);
        int s6 = __shfl(my, k + 6), s7 = __shfl(my, k + 7);
        a += bf2f(wb[s0 << 6]) + bf2f(wb[s1 << 6]) +
             bf2f(wb[s2 << 6]) + bf2f(wb[s3 << 6]) +
             bf2f(wb[s4 << 6]) + bf2f(wb[s5 << 6]) +
             bf2f(wb[s6 << 6]) + bf2f(wb[s7 << 6]);
      }
      for (; k < m; ++k) a += bf2f(wb[__shfl(my, k) << 6]);
    }
    o += a / fmaxf((float)n, 1.0f);
  }
  out[(v << 6) + lane] = o;
}

extern "C" void kernel_launch(void* const* d_in, const int* in_sizes, int n_in,
                              void* d_out, int out_size, void* d_ws, size_t ws_size,
                              hipStream_t stream) {
  const float* feat = (const float*)d_in[0];
  const float* W1   = (const float*)d_in[1];
  const float* b1   = (const float*)d_in[2];
  const float* W2   = (const float*)d_in[3];
  const float* b2   = (const float*)d_in[4];
  const int* es1 = (const int*)d_in[5];
  const int* ed1 = (const int*)d_in[6];
  const int* es2 = (const int*)d_in[7];
  const int* ed2 = (const int*)d_in[8];

  char* ws = (char*)d_ws;
  int* ghist           = (int*)(ws + 0);            // 114,954 ints = 459,816 B
  int* blksum          = (int*)(ws + 460000);       // 113 ints
  unsigned* sorted     = (unsigned*)(ws + 460800);  // 19.2 MB
  unsigned short* sorted2 = (unsigned short*)(ws + 20121600); // 9.6 MB
  int* offk            = (int*)(ws + 29721600);     // 2*200192 ints
  int* cntk            = (int*)(ws + 31323136);     // 2*200192 ints
  unsigned short* featb = (unsigned short*)(ws + 32924672);  // 12.8 MB
  unsigned short* s1m   = (unsigned short*)(ws + 45724672);  // 38.4 MB
  unsigned short* hb    = (unsigned short*)(ws + 84124672);  // 12.8 MB
  unsigned short* wh2   = (unsigned short*)(ws + 96924672);  // 19.2 MB
  unsigned short* w1t   = (unsigned short*)(ws + 116124672); // 98,304 B
  unsigned short* w2t   = (unsigned short*)(ws + 116222976); // 49,152 B

  prep_k<<<6538, 256, 0, stream>>>(feat, W1, W2, featb, w1t, w2t);
  count_k<<<2 * NCH, 1024, 0, stream>>>(ed1, ed2, ghist);
  scan1_k<<<SCAN_NBLK, 256, 0, stream>>>(ghist, blksum);
  scan2_k<<<1, 64, 0, stream>>>(blksum);
  scan3_k<<<SCAN_NBLK, 256, 0, stream>>>(ghist, blksum);
  scatter_k<<<2 * NCH, 1024, 0, stream>>>(es1, ed1, es2, ed2, ghist, sorted);
  sortb_k<<<2 * NB, 512, 0, stream>>>(ghist, sorted, sorted2, offk, cntk);
  agg1_k<<<12500, 256, 0, stream>>>(offk, cntk, sorted2, (const unsigned*)featb,
                                    (unsigned*)s1m);
  gemm1_k<<<782, 256, 0, stream>>>(s1m, cntk, w1t, b1, hb);
  gemm2_k<<<782, 256, 0, stream>>>(hb, w2t, b2, wh2);
  agg2f_k<<<12500, 256, 0, stream>>>(offk, cntk, sorted2, wh2, (float*)d_out);
}

// Round 6
// 418.691 us; speedup vs baseline: 7.2956x; 1.1146x over previous
//
#include <hip/hip_runtime.h>

typedef __attribute__((ext_vector_type(8))) short short8;
typedef __attribute__((ext_vector_type(4))) float floatx4;

#define NCH 294         // chunks per layer
#define CH 8192         // edges per chunk
#define NB 391          // coarse buckets (512 keys each)
#define NKP 200192      // padded key count (NB*512)

__device__ __forceinline__ unsigned short f2bf(float f) {
  unsigned u = __float_as_uint(f);
  u += 0x7FFFu + ((u >> 16) & 1u);
  return (unsigned short)(u >> 16);
}
__device__ __forceinline__ float blo(unsigned x) { return __uint_as_float(x << 16); }
__device__ __forceinline__ float bhi(unsigned x) { return __uint_as_float(x & 0xFFFF0000u); }

// ---- fused prep (feat->bf16, W transposes) + per-chunk bucket histogram ----
__global__ __launch_bounds__(1024) void prep_count_k(
    const float* __restrict__ feat, const float* __restrict__ W1,
    const float* __restrict__ W2, const int* __restrict__ ed1,
    const int* __restrict__ ed2, unsigned short* __restrict__ featb,
    unsigned short* __restrict__ w1t, unsigned short* __restrict__ w2t,
    int* __restrict__ ghist) {
  __shared__ int h[NB];
  if (blockIdx.x < 2 * NCH) {            // count role
    int tid = threadIdx.x;
    int layer = blockIdx.x >= NCH;
    int c = blockIdx.x - layer * NCH;
    const int* ed = layer ? ed2 : ed1;
    if (tid < NB) h[tid] = 0;
    __syncthreads();
    int j0 = c * CH;
    for (int it = 0; it < CH / 1024; ++it) {
      int j = j0 + it * 1024 + tid;
      if (j < 2400000) atomicAdd(&h[(ed[j] * 4 + j / 800000) >> 9], 1);
    }
    __syncthreads();
    if (tid < NB) ghist[(layer * NB + tid) * NCH + c] = h[tid];
  } else {                               // prep role
    int tid = (blockIdx.x - 2 * NCH) * 1024 + threadIdx.x;
    if (tid < 1600000) {
      float4 v = ((const float4*)feat)[tid];
      ushort4 o;
      o.x = f2bf(v.x); o.y = f2bf(v.y); o.z = f2bf(v.z); o.w = f2bf(v.w);
      ((ushort4*)featb)[tid] = o;
    } else if (tid < 1600000 + 49152) {
      int t = tid - 1600000;
      int r = t >> 14, rem = t & 16383, n = rem >> 7, k = rem & 127;
      w1t[t] = f2bf(W1[(r << 14) + (k << 7) + n]);
    } else if (tid < 1600000 + 49152 + 24576) {
      int t = tid - 1649152;
      int r = t >> 13, rem = t & 8191, n = rem >> 7, k = rem & 127;
      w2t[t] = f2bf(W2[(r << 13) + (k << 6) + n]);
    }
  }
}

// ---- per-(layer,bucket) scan of 294 chunk counts (in place) + bucket totals ----
__global__ __launch_bounds__(320) void scanb_k(int* __restrict__ ghist,
                                               int* __restrict__ btot) {
  __shared__ int wsum[5];
  int t = threadIdx.x, lane = t & 63, w = t >> 6;
  int base = blockIdx.x * NCH;
  int v = (t < NCH) ? ghist[base + t] : 0;
  int inc = v;
#pragma unroll
  for (int o = 1; o < 64; o <<= 1) {
    int u = __shfl_up(inc, o);
    if (lane >= o) inc += u;
  }
  if (lane == 63) wsum[w] = inc;
  __syncthreads();
  int woff = 0;
#pragma unroll
  for (int k = 0; k < 5; ++k) if (k < w) woff += wsum[k];
  if (t < NCH) ghist[base + t] = woff + inc - v;
  if (t == 319) btot[blockIdx.x] = woff + inc;
}

// ---- single-wave scan of the 782 bucket totals -> bucket bases + sentinel ----
__global__ __launch_bounds__(64) void scanc_k(const int* __restrict__ btot,
                                              int* __restrict__ bbase) {
  int lane = threadIdx.x;
  int carry = 0;
  for (int g0 = 0; g0 < 832; g0 += 64) {
    int i = g0 + lane;
    int v = (i < 2 * NB) ? btot[i] : 0;
    int inc = v;
#pragma unroll
    for (int o = 1; o < 64; o <<= 1) {
      int u = __shfl_up(inc, o);
      if (lane >= o) inc += u;
    }
    if (i < 2 * NB) bbase[i] = carry + inc - v;
    carry += __shfl(inc, 63);
  }
  if (lane == 0) bbase[2 * NB] = carry;
}

// ---- chunk-local LDS-cursor scatter -> sorted[] (src | within-bucket-key<<16) ----
__global__ __launch_bounds__(1024) void scatter_k(
    const int* __restrict__ es1, const int* __restrict__ ed1,
    const int* __restrict__ es2, const int* __restrict__ ed2,
    const int* __restrict__ ghist, const int* __restrict__ bbase,
    unsigned* __restrict__ sorted) {
  __shared__ int cur[NB];
  int tid = threadIdx.x;
  int layer = blockIdx.x >= NCH;
  int c = blockIdx.x - layer * NCH;
  const int* es = layer ? es2 : es1;
  const int* ed = layer ? ed2 : ed1;
  if (tid < NB)
    cur[tid] = bbase[layer * NB + tid] + ghist[(layer * NB + tid) * NCH + c];
  __syncthreads();
  int j0 = c * CH;
  for (int it = 0; it < CH / 1024; ++it) {
    int j = j0 + it * 1024 + tid;
    if (j < 2400000) {
      int key = ed[j] * 4 + j / 800000;
      int pos = atomicAdd(&cur[key >> 9], 1);
      sorted[pos] = (unsigned)es[j] | ((unsigned)(key & 511) << 16);
    }
  }
}

// ---- per-bucket micro-sort: bucket-grouped -> key-sorted ushort srcs + off/cnt ----
__global__ __launch_bounds__(512) void sortb_k(
    const int* __restrict__ bbase, const unsigned* __restrict__ sorted,
    unsigned short* __restrict__ sorted2, int* __restrict__ offk,
    int* __restrict__ cntk) {
  __shared__ int hist[512], cur[512];
  int tid = threadIdx.x;
  int layer = blockIdx.x >= NB;
  int b = blockIdx.x - layer * NB;
  int start = bbase[blockIdx.x];
  int end = bbase[blockIdx.x + 1];
  hist[tid] = 0;
  __syncthreads();
  for (int e = start + tid; e < end; e += 512)
    atomicAdd(&hist[sorted[e] >> 16], 1);
  __syncthreads();
  if (tid < 64) {
    int carry = 0;
    for (int g0 = 0; g0 < 512; g0 += 64) {
      int h = hist[g0 + tid];
      int inc = h;
#pragma unroll
      for (int o = 1; o < 64; o <<= 1) {
        int u = __shfl_up(inc, o);
        if (tid >= o) inc += u;
      }
      int excl = carry + inc - h;
      cur[g0 + tid] = excl;
      int lb = layer * NKP + (b << 9) + g0 + tid;
      offk[lb] = start + excl;
      cntk[lb] = h;
      carry += __shfl(inc, 63);
    }
  }
  __syncthreads();
  for (int e = start + tid; e < end; e += 512) {
    unsigned v = sorted[e];
    int p = atomicAdd(&cur[v >> 16], 1);
    sorted2[start + p] = (unsigned short)(v & 0xFFFFu);
  }
}

// ---- layer-1 agg: wave per node, 2 edges per vmem instr (uint2/lane) ----
__global__ __launch_bounds__(256) void agg1_k(
    const int* __restrict__ offk, const int* __restrict__ cntk,
    const unsigned short* __restrict__ sorted2,
    const uint2* __restrict__ fb2, uint2* __restrict__ s1m2) {
  int lane = threadIdx.x & 63;
  int half = lane >> 5, l32 = lane & 31;
  int v = blockIdx.x * 4 + (threadIdx.x >> 6);
  if (v >= 50000) return;
  const uint2* fb = fb2 + l32;
#pragma unroll
  for (int r = 0; r < 3; ++r) {
    int key = v * 4 + r;
    int base = offk[key], n = cntk[key];
    float a0 = 0.f, a1 = 0.f, a2 = 0.f, a3 = 0.f;
    for (int jb = 0; jb < n; jb += 64) {
      int m = n - jb; if (m > 64) m = 64;
      int my = (lane < m) ? (int)sorted2[base + jb + lane] : 0;
      int k = 0;
      for (; k + 8 <= m; k += 8) {
        int i0 = __shfl(my, k + half);
        int i1 = __shfl(my, k + 2 + half);
        int i2 = __shfl(my, k + 4 + half);
        int i3 = __shfl(my, k + 6 + half);
        uint2 p0 = fb[i0 << 5], p1 = fb[i1 << 5];
        uint2 p2 = fb[i2 << 5], p3 = fb[i3 << 5];
        a0 += blo(p0.x) + blo(p1.x) + blo(p2.x) + blo(p3.x);
        a1 += bhi(p0.x) + bhi(p1.x) + bhi(p2.x) + bhi(p3.x);
        a2 += blo(p0.y) + blo(p1.y) + blo(p2.y) + blo(p3.y);
        a3 += bhi(p0.y) + bhi(p1.y) + bhi(p2.y) + bhi(p3.y);
      }
      for (; k + 2 <= m; k += 2) {
        int i0 = __shfl(my, k + half);
        uint2 p = fb[i0 << 5];
        a0 += blo(p.x); a1 += bhi(p.x); a2 += blo(p.y); a3 += bhi(p.y);
      }
      if (k < m) {
        int i0 = __shfl(my, k);
        if (half == 0) {
          uint2 p = fb[i0 << 5];
          a0 += blo(p.x); a1 += bhi(p.x); a2 += blo(p.y); a3 += bhi(p.y);
        }
      }
    }
    a0 += __shfl_xor(a0, 32); a1 += __shfl_xor(a1, 32);
    a2 += __shfl_xor(a2, 32); a3 += __shfl_xor(a3, 32);
    float inv = 1.0f / fmaxf((float)n, 1.0f);
    if (half == 0) {
      uint2 o;
      o.x = ((unsigned)f2bf(a1 * inv) << 16) | (unsigned)f2bf(a0 * inv);
      o.y = ((unsigned)f2bf(a3 * inv) << 16) | (unsigned)f2bf(a2 * inv);
      s1m2[(r * 50000 + v) * 32 + l32] = o;
    }
  }
}

// ---- fused GEMM1+GEMM2 via LDS h-tile: 64 nodes/block ----
__global__ __launch_bounds__(256) void gemm12_k(
    const unsigned short* __restrict__ s1m, const int* __restrict__ cntk,
    const unsigned short* __restrict__ w1t, const float* __restrict__ b1,
    const unsigned short* __restrict__ w2t, const float* __restrict__ b2,
    unsigned short* __restrict__ wh2) {
  __shared__ unsigned short hs[64 * 136];   // row stride 272 B: 2-way bank alias (free)
  int lane = threadIdx.x & 63;
  int wave = threadIdx.x >> 6;
  int rbase = blockIdx.x * 64 + wave * 16;
  int arow = rbase + (lane & 15);
  int anode = arow < 50000 ? arow : 49999;
  int kg = lane >> 4;

  const floatx4 fzero = {0.f, 0.f, 0.f, 0.f};
  floatx4 acc1[8];
#pragma unroll
  for (int f = 0; f < 8; ++f) acc1[f] = fzero;

#pragma unroll
  for (int ks = 0; ks < 12; ++ks) {
    int r = ks >> 2;
    int k0 = ((ks & 3) << 5) + (kg << 3);
    short8 af = *(const short8*)(s1m + ((r * 50000 + anode) << 7) + k0);
#pragma unroll
    for (int f = 0; f < 8; ++f) {
      int n = (f << 4) + (lane & 15);
      short8 bf = *(const short8*)(w1t + (r << 14) + (n << 7) + k0);
      acc1[f] = __builtin_amdgcn_mfma_f32_16x16x32_bf16(af, bf, acc1[f], 0, 0, 0);
    }
  }

  int orow_l = wave * 16 + ((lane >> 4) << 2);
  float msk[4][3];
#pragma unroll
  for (int reg = 0; reg < 4; ++reg) {
    int nd = blockIdx.x * 64 + orow_l + reg; if (nd > 49999) nd = 49999;
#pragma unroll
    for (int r = 0; r < 3; ++r)
      msk[reg][r] = cntk[nd * 4 + r] ? 1.0f : 0.0f;
  }
#pragma unroll
  for (int f = 0; f < 8; ++f) {
    int col = (f << 4) + (lane & 15);
    float bb0 = b1[col], bb1 = b1[128 + col], bb2 = b1[256 + col];
#pragma unroll
    for (int reg = 0; reg < 4; ++reg) {
      float v = acc1[f][reg] + msk[reg][0] * bb0 + msk[reg][1] * bb1 + msk[reg][2] * bb2;
      v = (v >= 0.f) ? v : 0.01f * v;
      hs[(orow_l + reg) * 136 + col] = f2bf(v);
    }
  }
  __syncthreads();

  floatx4 acc2[12];
#pragma unroll
  for (int f = 0; f < 12; ++f) acc2[f] = fzero;
  int arow_l = wave * 16 + (lane & 15);
#pragma unroll
  for (int ks = 0; ks < 4; ++ks) {
    int k0 = (ks << 5) + (kg << 3);
    short8 af = *(const short8*)(hs + arow_l * 136 + k0);
#pragma unroll
    for (int f = 0; f < 12; ++f) {
      int col = (f << 4) + (lane & 15);
      int r = col >> 6, c0 = col & 63;
      short8 bf = *(const short8*)(w2t + (r << 13) + (c0 << 7) + k0);
      acc2[f] = __builtin_amdgcn_mfma_f32_16x16x32_bf16(af, bf, acc2[f], 0, 0, 0);
    }
  }
  int orow = rbase + ((lane >> 4) << 2);
#pragma unroll
  for (int f = 0; f < 12; ++f) {
    int col = (f << 4) + (lane & 15);
    int r = col >> 6, c0 = col & 63;
    float bv = b2[(r << 6) + c0];
#pragma unroll
    for (int reg = 0; reg < 4; ++reg) {
      int nd = orow + reg;
      if (nd < 50000) {
        float v = acc2[f][reg] + bv;
        wh2[((r * 50000 + nd) << 6) + c0] = f2bf(v);
      }
    }
  }
}

// ---- layer-2 agg + final: wave per node, 2 edges per vmem instr (uint/lane) ----
__global__ __launch_bounds__(256) void agg2f_k(
    const int* __restrict__ offk, const int* __restrict__ cntk,
    const unsigned short* __restrict__ sorted2,
    const unsigned* __restrict__ wh24, float* __restrict__ out) {
  int lane = threadIdx.x & 63;
  int half = lane >> 5, l32 = lane & 31;
  int v = blockIdx.x * 4 + (threadIdx.x >> 6);
  if (v >= 50000) return;
  const unsigned* wb = wh24 + l32;
  float o0 = 0.f, o1 = 0.f;
#pragma unroll
  for (int r = 0; r < 3; ++r) {
    int key = NKP + v * 4 + r;
    int base = offk[key], n = cntk[key];
    const unsigned* wbr = wb + r * 1600000;   // r*50000*32
    float a0 = 0.f, a1 = 0.f;
    for (int jb = 0; jb < n; jb += 64) {
      int m = n - jb; if (m > 64) m = 64;
      int my = (lane < m) ? (int)sorted2[base + jb + lane] : 0;
      int k = 0;
      for (; k + 8 <= m; k += 8) {
        int i0 = __shfl(my, k + half);
        int i1 = __shfl(my, k + 2 + half);
        int i2 = __shfl(my, k + 4 + half);
        int i3 = __shfl(my, k + 6 + half);
        unsigned p0 = wbr[i0 << 5], p1 = wbr[i1 << 5];
        unsigned p2 = wbr[i2 << 5], p3 = wbr[i3 << 5];
        a0 += blo(p0) + blo(p1) + blo(p2) + blo(p3);
        a1 += bhi(p0) + bhi(p1) + bhi(p2) + bhi(p3);
      }
      for (; k + 2 <= m; k += 2) {
        unsigned p = wbr[__shfl(my, k + half) << 5];
        a0 += blo(p); a1 += bhi(p);
      }
      if (k < m) {
        int i0 = __shfl(my, k);
        if (half == 0) {
          unsigned p = wbr[i0 << 5];
          a0 += blo(p); a1 += bhi(p);
        }
      }
    }
    a0 += __shfl_xor(a0, 32); a1 += __shfl_xor(a1, 32);
    float inv = 1.0f / fmaxf((float)n, 1.0f);
    o0 += a0 * inv; o1 += a1 * inv;
  }
  if (half == 0) {
    float2 o; o.x = o0; o.y = o1;
    ((float2*)out)[v * 32 + l32] = o;
  }
}

extern "C" void kernel_launch(void* const* d_in, const int* in_sizes, int n_in,
                              void* d_out, int out_size, void* d_ws, size_t ws_size,
                              hipStream_t stream) {
  const float* feat = (const float*)d_in[0];
  const float* W1   = (const float*)d_in[1];
  const float* b1   = (const float*)d_in[2];
  const float* W2   = (const float*)d_in[3];
  const float* b2   = (const float*)d_in[4];
  const int* es1 = (const int*)d_in[5];
  const int* ed1 = (const int*)d_in[6];
  const int* es2 = (const int*)d_in[7];
  const int* ed2 = (const int*)d_in[8];

  char* ws = (char*)d_ws;
  int* ghist           = (int*)(ws + 0);             // 229,908 ints = 919,632 B
  int* btot            = (int*)(ws + 920000);        // 782 ints
  int* bbase           = (int*)(ws + 924000);        // 783 ints
  unsigned* sorted     = (unsigned*)(ws + 928000);   // 19.2 MB
  unsigned short* sorted2 = (unsigned short*)(ws + 20128000); // 9.6 MB
  int* offk            = (int*)(ws + 29728000);      // 2*200192 ints
  int* cntk            = (int*)(ws + 31329536);      // 2*200192 ints
  unsigned short* featb = (unsigned short*)(ws + 32931072);  // 12.8 MB
  unsigned short* s1m   = (unsigned short*)(ws + 45731072);  // 38.4 MB
  unsigned short* wh2   = (unsigned short*)(ws + 84131072);  // 19.2 MB
  unsigned short* w1t   = (unsigned short*)(ws + 103331072); // 98,304 B
  unsigned short* w2t   = (unsigned short*)(ws + 103429376); // 49,152 B

  prep_count_k<<<2 * NCH + 1635, 1024, 0, stream>>>(feat, W1, W2, ed1, ed2,
                                                    featb, w1t, w2t, ghist);
  scanb_k<<<2 * NB, 320, 0, stream>>>(ghist, btot);
  scanc_k<<<1, 64, 0, stream>>>(btot, bbase);
  scatter_k<<<2 * NCH, 1024, 0, stream>>>(es1, ed1, es2, ed2, ghist, bbase, sorted);
  sortb_k<<<2 * NB, 512, 0, stream>>>(bbase, sorted, sorted2, offk, cntk);
  agg1_k<<<12500, 256, 0, stream>>>(offk, cntk, sorted2, (const uint2*)featb,
                                    (uint2*)s1m);
  gemm12_k<<<782, 256, 0, stream>>>(s1m, cntk, w1t, b1, w2t, b2, wh2);
  agg2f_k<<<12500, 256, 0, stream>>>(offk, cntk, sorted2, (const unsigned*)wh2,
                                     (float*)d_out);
}

// Round 7
// 409.274 us; speedup vs baseline: 7.4635x; 1.0230x over previous
//
#include <hip/hip_runtime.h>

typedef __attribute__((ext_vector_type(8))) short short8;
typedef __attribute__((ext_vector_type(4))) float floatx4;

#define NCH 294         // chunks per layer
#define CH 8192         // edges per chunk
#define NB 391          // coarse buckets (512 keys each)
#define NKP 200192      // padded key count (NB*512)

__device__ __forceinline__ unsigned short f2bf(float f) {
  unsigned u = __float_as_uint(f);
  u += 0x7FFFu + ((u >> 16) & 1u);
  return (unsigned short)(u >> 16);
}
__device__ __forceinline__ float blo(unsigned x) { return __uint_as_float(x << 16); }
__device__ __forceinline__ float bhi(unsigned x) { return __uint_as_float(x & 0xFFFF0000u); }

// ---- fused prep (feat->bf16, W transposes) + per-chunk bucket histogram ----
__global__ __launch_bounds__(1024) void prep_count_k(
    const float* __restrict__ feat, const float* __restrict__ W1,
    const float* __restrict__ W2, const int* __restrict__ ed1,
    const int* __restrict__ ed2, unsigned short* __restrict__ featb,
    unsigned short* __restrict__ w1t, unsigned short* __restrict__ w2t,
    int* __restrict__ ghist) {
  __shared__ int h[NB];
  if (blockIdx.x < 2 * NCH) {            // count role
    int tid = threadIdx.x;
    int layer = blockIdx.x >= NCH;
    int c = blockIdx.x - layer * NCH;
    const int* ed = layer ? ed2 : ed1;
    if (tid < NB) h[tid] = 0;
    __syncthreads();
    int j0 = c * CH;
    for (int it = 0; it < CH / 1024; ++it) {
      int j = j0 + it * 1024 + tid;
      if (j < 2400000) atomicAdd(&h[(ed[j] * 4 + j / 800000) >> 9], 1);
    }
    __syncthreads();
    if (tid < NB) ghist[(layer * NB + tid) * NCH + c] = h[tid];
  } else {                               // prep role
    int tid = (blockIdx.x - 2 * NCH) * 1024 + threadIdx.x;
    if (tid < 1600000) {
      float4 v = ((const float4*)feat)[tid];
      ushort4 o;
      o.x = f2bf(v.x); o.y = f2bf(v.y); o.z = f2bf(v.z); o.w = f2bf(v.w);
      ((ushort4*)featb)[tid] = o;
    } else if (tid < 1600000 + 49152) {
      int t = tid - 1600000;
      int r = t >> 14, rem = t & 16383, n = rem >> 7, k = rem & 127;
      w1t[t] = f2bf(W1[(r << 14) + (k << 7) + n]);
    } else if (tid < 1600000 + 49152 + 24576) {
      int t = tid - 1649152;
      int r = t >> 13, rem = t & 8191, n = rem >> 7, k = rem & 127;
      w2t[t] = f2bf(W2[(r << 13) + (k << 6) + n]);
    }
  }
}

// ---- per-(layer,bucket) scan of 294 chunk counts (in place) + bucket totals ----
__global__ __launch_bounds__(320) void scanb_k(int* __restrict__ ghist,
                                               int* __restrict__ btot) {
  __shared__ int wsum[5];
  int t = threadIdx.x, lane = t & 63, w = t >> 6;
  int base = blockIdx.x * NCH;
  int v = (t < NCH) ? ghist[base + t] : 0;
  int inc = v;
#pragma unroll
  for (int o = 1; o < 64; o <<= 1) {
    int u = __shfl_up(inc, o);
    if (lane >= o) inc += u;
  }
  if (lane == 63) wsum[w] = inc;
  __syncthreads();
  int woff = 0;
#pragma unroll
  for (int k = 0; k < 5; ++k) if (k < w) woff += wsum[k];
  if (t < NCH) ghist[base + t] = woff + inc - v;
  if (t == 319) btot[blockIdx.x] = woff + inc;
}

// ---- single-wave scan of the 782 bucket totals -> bucket bases + sentinel ----
__global__ __launch_bounds__(64) void scanc_k(const int* __restrict__ btot,
                                              int* __restrict__ bbase) {
  int lane = threadIdx.x;
  int carry = 0;
  for (int g0 = 0; g0 < 832; g0 += 64) {
    int i = g0 + lane;
    int v = (i < 2 * NB) ? btot[i] : 0;
    int inc = v;
#pragma unroll
    for (int o = 1; o < 64; o <<= 1) {
      int u = __shfl_up(inc, o);
      if (lane >= o) inc += u;
    }
    if (i < 2 * NB) bbase[i] = carry + inc - v;
    carry += __shfl(inc, 63);
  }
  if (lane == 0) bbase[2 * NB] = carry;
}

// ---- chunk-local LDS-cursor scatter -> sorted[] (src | within-bucket-key<<16) ----
__global__ __launch_bounds__(1024) void scatter_k(
    const int* __restrict__ es1, const int* __restrict__ ed1,
    const int* __restrict__ es2, const int* __restrict__ ed2,
    const int* __restrict__ ghist, const int* __restrict__ bbase,
    unsigned* __restrict__ sorted) {
  __shared__ int cur[NB];
  int tid = threadIdx.x;
  int layer = blockIdx.x >= NCH;
  int c = blockIdx.x - layer * NCH;
  const int* es = layer ? es2 : es1;
  const int* ed = layer ? ed2 : ed1;
  if (tid < NB)
    cur[tid] = bbase[layer * NB + tid] + ghist[(layer * NB + tid) * NCH + c];
  __syncthreads();
  int j0 = c * CH;
  for (int it = 0; it < CH / 1024; ++it) {
    int j = j0 + it * 1024 + tid;
    if (j < 2400000) {
      int key = ed[j] * 4 + j / 800000;
      int pos = atomicAdd(&cur[key >> 9], 1);
      sorted[pos] = (unsigned)es[j] | ((unsigned)(key & 511) << 16);
    }
  }
}

// ---- per-bucket micro-sort: bucket-grouped -> key-sorted ushort srcs + off/cnt ----
__global__ __launch_bounds__(512) void sortb_k(
    const int* __restrict__ bbase, const unsigned* __restrict__ sorted,
    unsigned short* __restrict__ sorted2, int* __restrict__ offk,
    int* __restrict__ cntk) {
  __shared__ int hist[512], cur[512];
  int tid = threadIdx.x;
  int layer = blockIdx.x >= NB;
  int b = blockIdx.x - layer * NB;
  int start = bbase[blockIdx.x];
  int end = bbase[blockIdx.x + 1];
  hist[tid] = 0;
  __syncthreads();
  for (int e = start + tid; e < end; e += 512)
    atomicAdd(&hist[sorted[e] >> 16], 1);
  __syncthreads();
  if (tid < 64) {
    int carry = 0;
    for (int g0 = 0; g0 < 512; g0 += 64) {
      int h = hist[g0 + tid];
      int inc = h;
#pragma unroll
      for (int o = 1; o < 64; o <<= 1) {
        int u = __shfl_up(inc, o);
        if (tid >= o) inc += u;
      }
      int excl = carry + inc - h;
      cur[g0 + tid] = excl;
      int lb = layer * NKP + (b << 9) + g0 + tid;
      offk[lb] = start + excl;
      cntk[lb] = h;
      carry += __shfl(inc, 63);
    }
  }
  __syncthreads();
  for (int e = start + tid; e < end; e += 512) {
    unsigned v = sorted[e];
    int p = atomicAdd(&cur[v >> 16], 1);
    sorted2[start + p] = (unsigned short)(v & 0xFFFFu);
  }
}

// ---- layer-1 agg: wave per node, 2 edges per vmem instr (uint2/lane) ----
__global__ __launch_bounds__(256) void agg1_k(
    const int* __restrict__ offk, const int* __restrict__ cntk,
    const unsigned short* __restrict__ sorted2,
    const uint2* __restrict__ fb2, uint2* __restrict__ s1m2) {
  int lane = threadIdx.x & 63;
  int half = lane >> 5, l32 = lane & 31;
  int v = blockIdx.x * 4 + (threadIdx.x >> 6);
  if (v >= 50000) return;
  const uint2* fb = fb2 + l32;
#pragma unroll
  for (int r = 0; r < 3; ++r) {
    int key = v * 4 + r;
    int base = offk[key], n = cntk[key];
    float a0 = 0.f, a1 = 0.f, a2 = 0.f, a3 = 0.f;
    for (int jb = 0; jb < n; jb += 64) {
      int m = n - jb; if (m > 64) m = 64;
      int my = (lane < m) ? (int)sorted2[base + jb + lane] : 0;
      int k = 0;
      for (; k + 8 <= m; k += 8) {
        int i0 = __shfl(my, k + half);
        int i1 = __shfl(my, k + 2 + half);
        int i2 = __shfl(my, k + 4 + half);
        int i3 = __shfl(my, k + 6 + half);
        uint2 p0 = fb[i0 << 5], p1 = fb[i1 << 5];
        uint2 p2 = fb[i2 << 5], p3 = fb[i3 << 5];
        a0 += blo(p0.x) + blo(p1.x) + blo(p2.x) + blo(p3.x);
        a1 += bhi(p0.x) + bhi(p1.x) + bhi(p2.x) + bhi(p3.x);
        a2 += blo(p0.y) + blo(p1.y) + blo(p2.y) + blo(p3.y);
        a3 += bhi(p0.y) + bhi(p1.y) + bhi(p2.y) + bhi(p3.y);
      }
      for (; k + 2 <= m; k += 2) {
        int i0 = __shfl(my, k + half);
        uint2 p = fb[i0 << 5];
        a0 += blo(p.x); a1 += bhi(p.x); a2 += blo(p.y); a3 += bhi(p.y);
      }
      if (k < m) {
        int i0 = __shfl(my, k);
        if (half == 0) {
          uint2 p = fb[i0 << 5];
          a0 += blo(p.x); a1 += bhi(p.x); a2 += blo(p.y); a3 += bhi(p.y);
        }
      }
    }
    a0 += __shfl_xor(a0, 32); a1 += __shfl_xor(a1, 32);
    a2 += __shfl_xor(a2, 32); a3 += __shfl_xor(a3, 32);
    float inv = 1.0f / fmaxf((float)n, 1.0f);
    if (half == 0) {
      uint2 o;
      o.x = ((unsigned)f2bf(a1 * inv) << 16) | (unsigned)f2bf(a0 * inv);
      o.y = ((unsigned)f2bf(a3 * inv) << 16) | (unsigned)f2bf(a2 * inv);
      s1m2[(r * 50000 + v) * 32 + l32] = o;
    }
  }
}

// ---- fused GEMM1+GEMM2, 16 rows/block, waves split N: 3125 blocks ----
// gemm1: wave w owns cols [32w,32w+32) of h (2 frags); gemm2: cols [48w,48w+48) of Wh2.
__global__ __launch_bounds__(256) void gemm12_k(
    const unsigned short* __restrict__ s1m, const int* __restrict__ cntk,
    const unsigned short* __restrict__ w1t, const float* __restrict__ b1,
    const unsigned short* __restrict__ w2t, const float* __restrict__ b2,
    unsigned short* __restrict__ wh2) {
  __shared__ unsigned short hs[16 * 136];
  int lane = threadIdx.x & 63;
  int w = threadIdx.x >> 6;
  int m16 = lane & 15, kg = lane >> 4;
  int rbase = blockIdx.x * 16;          // 50000 = 3125*16, no bounds checks
  int anode = rbase + m16;

  const floatx4 fzero = {0.f, 0.f, 0.f, 0.f};
  floatx4 acc1[2] = {fzero, fzero};
#pragma unroll
  for (int ks = 0; ks < 12; ++ks) {
    int r = ks >> 2;
    int k0 = ((ks & 3) << 5) + (kg << 3);
    short8 af = *(const short8*)(s1m + ((r * 50000 + anode) << 7) + k0);
#pragma unroll
    for (int f = 0; f < 2; ++f) {
      int n = (w << 5) + (f << 4) + m16;
      short8 bf = *(const short8*)(w1t + (r << 14) + (n << 7) + k0);
      acc1[f] = __builtin_amdgcn_mfma_f32_16x16x32_bf16(af, bf, acc1[f], 0, 0, 0);
    }
  }

  int orow = kg << 2;
  float msk[4][3];
#pragma unroll
  for (int reg = 0; reg < 4; ++reg) {
    int nd = rbase + orow + reg;
#pragma unroll
    for (int r = 0; r < 3; ++r) msk[reg][r] = cntk[nd * 4 + r] ? 1.0f : 0.0f;
  }
#pragma unroll
  for (int f = 0; f < 2; ++f) {
    int col = (w << 5) + (f << 4) + m16;
    float bb0 = b1[col], bb1 = b1[128 + col], bb2 = b1[256 + col];
#pragma unroll
    for (int reg = 0; reg < 4; ++reg) {
      float v = acc1[f][reg] + msk[reg][0] * bb0 + msk[reg][1] * bb1 + msk[reg][2] * bb2;
      v = (v >= 0.f) ? v : 0.01f * v;
      hs[(orow + reg) * 136 + col] = f2bf(v);
    }
  }
  __syncthreads();

  floatx4 acc2[3] = {fzero, fzero, fzero};
#pragma unroll
  for (int ks = 0; ks < 4; ++ks) {
    int k0 = (ks << 5) + (kg << 3);
    short8 af = *(const short8*)(hs + m16 * 136 + k0);
#pragma unroll
    for (int f = 0; f < 3; ++f) {
      int col = w * 48 + (f << 4) + m16;
      int r = col >> 6, c0 = col & 63;
      short8 bf = *(const short8*)(w2t + (r << 13) + (c0 << 7) + k0);
      acc2[f] = __builtin_amdgcn_mfma_f32_16x16x32_bf16(af, bf, acc2[f], 0, 0, 0);
    }
  }
#pragma unroll
  for (int f = 0; f < 3; ++f) {
    int col = w * 48 + (f << 4) + m16;
    int r = col >> 6, c0 = col & 63;
    float bv = b2[(r << 6) + c0];
#pragma unroll
    for (int reg = 0; reg < 4; ++reg) {
      int nd = rbase + orow + reg;
      wh2[((r * 50000 + nd) << 6) + c0] = f2bf(acc2[f][reg] + bv);
    }
  }
}

// ---- layer-2 agg + final: wave per node, 2 edges per vmem instr (uint/lane) ----
__global__ __launch_bounds__(256) void agg2f_k(
    const int* __restrict__ offk, const int* __restrict__ cntk,
    const unsigned short* __restrict__ sorted2,
    const unsigned* __restrict__ wh24, float* __restrict__ out) {
  int lane = threadIdx.x & 63;
  int half = lane >> 5, l32 = lane & 31;
  int v = blockIdx.x * 4 + (threadIdx.x >> 6);
  if (v >= 50000) return;
  const unsigned* wb = wh24 + l32;
  float o0 = 0.f, o1 = 0.f;
#pragma unroll
  for (int r = 0; r < 3; ++r) {
    int key = NKP + v * 4 + r;
    int base = offk[key], n = cntk[key];
    const unsigned* wbr = wb + r * 1600000;   // r*50000*32
    float a0 = 0.f, a1 = 0.f;
    for (int jb = 0; jb < n; jb += 64) {
      int m = n - jb; if (m > 64) m = 64;
      int my = (lane < m) ? (int)sorted2[base + jb + lane] : 0;
      int k = 0;
      for (; k + 8 <= m; k += 8) {
        int i0 = __shfl(my, k + half);
        int i1 = __shfl(my, k + 2 + half);
        int i2 = __shfl(my, k + 4 + half);
        int i3 = __shfl(my, k + 6 + half);
        unsigned p0 = wbr[i0 << 5], p1 = wbr[i1 << 5];
        unsigned p2 = wbr[i2 << 5], p3 = wbr[i3 << 5];
        a0 += blo(p0) + blo(p1) + blo(p2) + blo(p3);
        a1 += bhi(p0) + bhi(p1) + bhi(p2) + bhi(p3);
      }
      for (; k + 2 <= m; k += 2) {
        unsigned p = wbr[__shfl(my, k + half) << 5];
        a0 += blo(p); a1 += bhi(p);
      }
      if (k < m) {
        int i0 = __shfl(my, k);
        if (half == 0) {
          unsigned p = wbr[i0 << 5];
          a0 += blo(p); a1 += bhi(p);
        }
      }
    }
    a0 += __shfl_xor(a0, 32); a1 += __shfl_xor(a1, 32);
    float inv = 1.0f / fmaxf((float)n, 1.0f);
    o0 += a0 * inv; o1 += a1 * inv;
  }
  if (half == 0) {
    float2 o; o.x = o0; o.y = o1;
    ((float2*)out)[v * 32 + l32] = o;
  }
}

extern "C" void kernel_launch(void* const* d_in, const int* in_sizes, int n_in,
                              void* d_out, int out_size, void* d_ws, size_t ws_size,
                              hipStream_t stream) {
  const float* feat = (const float*)d_in[0];
  const float* W1   = (const float*)d_in[1];
  const float* b1   = (const float*)d_in[2];
  const float* W2   = (const float*)d_in[3];
  const float* b2   = (const float*)d_in[4];
  const int* es1 = (const int*)d_in[5];
  const int* ed1 = (const int*)d_in[6];
  const int* es2 = (const int*)d_in[7];
  const int* ed2 = (const int*)d_in[8];

  char* ws = (char*)d_ws;
  int* ghist           = (int*)(ws + 0);             // 229,908 ints = 919,632 B
  int* btot            = (int*)(ws + 920000);        // 782 ints
  int* bbase           = (int*)(ws + 924000);        // 783 ints
  unsigned* sorted     = (unsigned*)(ws + 928000);   // 19.2 MB
  unsigned short* sorted2 = (unsigned short*)(ws + 20128000); // 9.6 MB
  int* offk            = (int*)(ws + 29728000);      // 2*200192 ints
  int* cntk            = (int*)(ws + 31329536);      // 2*200192 ints
  unsigned short* featb = (unsigned short*)(ws + 32931072);  // 12.8 MB
  unsigned short* s1m   = (unsigned short*)(ws + 45731072);  // 38.4 MB
  unsigned short* wh2   = (unsigned short*)(ws + 84131072);  // 19.2 MB
  unsigned short* w1t   = (unsigned short*)(ws + 103331072); // 98,304 B
  unsigned short* w2t   = (unsigned short*)(ws + 103429376); // 49,152 B

  prep_count_k<<<2 * NCH + 1635, 1024, 0, stream>>>(feat, W1, W2, ed1, ed2,
                                                    featb, w1t, w2t, ghist);
  scanb_k<<<2 * NB, 320, 0, stream>>>(ghist, btot);
  scanc_k<<<1, 64, 0, stream>>>(btot, bbase);
  scatter_k<<<2 * NCH, 1024, 0, stream>>>(es1, ed1, es2, ed2, ghist, bbase, sorted);
  sortb_k<<<2 * NB, 512, 0, stream>>>(bbase, sorted, sorted2, offk, cntk);
  agg1_k<<<12500, 256, 0, stream>>>(offk, cntk, sorted2, (const uint2*)featb,
                                    (uint2*)s1m);
  gemm12_k<<<3125, 256, 0, stream>>>(s1m, cntk, w1t, b1, w2t, b2, wh2);
  agg2f_k<<<12500, 256, 0, stream>>>(offk, cntk, sorted2, (const unsigned*)wh2,
                                     (float*)d_out);
}

// Round 8
// 392.162 us; speedup vs baseline: 7.7891x; 1.0436x over previous
//
#include <hip/hip_runtime.h>

typedef __attribute__((ext_vector_type(8))) short short8;
typedef __attribute__((ext_vector_type(4))) float floatx4;

#define NCH 294         // chunks per layer
#define CH 8192         // edges per chunk
#define NB 391          // coarse buckets (512 keys each)
#define NKP 200192      // padded key count (NB*512)

__device__ __forceinline__ unsigned short f2bf(float f) {
  unsigned u = __float_as_uint(f);
  u += 0x7FFFu + ((u >> 16) & 1u);
  return (unsigned short)(u >> 16);
}
__device__ __forceinline__ float blo(unsigned x) { return __uint_as_float(x << 16); }
__device__ __forceinline__ float bhi(unsigned x) { return __uint_as_float(x & 0xFFFF0000u); }

// ---- fused prep (feat->bf16, W transposes) + per-chunk bucket histogram ----
__global__ __launch_bounds__(1024) void prep_count_k(
    const float* __restrict__ feat, const float* __restrict__ W1,
    const float* __restrict__ W2, const int* __restrict__ ed1,
    const int* __restrict__ ed2, unsigned short* __restrict__ featb,
    unsigned short* __restrict__ w1t, unsigned short* __restrict__ w2t,
    int* __restrict__ ghist) {
  __shared__ int h[NB];
  if (blockIdx.x < 2 * NCH) {            // count role
    int tid = threadIdx.x;
    int layer = blockIdx.x >= NCH;
    int c = blockIdx.x - layer * NCH;
    const int* ed = layer ? ed2 : ed1;
    if (tid < NB) h[tid] = 0;
    __syncthreads();
    int j0 = c * CH;
    for (int it = 0; it < CH / 1024; ++it) {
      int j = j0 + it * 1024 + tid;
      if (j < 2400000) atomicAdd(&h[(ed[j] * 4 + j / 800000) >> 9], 1);
    }
    __syncthreads();
    if (tid < NB) ghist[(layer * NB + tid) * NCH + c] = h[tid];
  } else {                               // prep role
    int tid = (blockIdx.x - 2 * NCH) * 1024 + threadIdx.x;
    if (tid < 1600000) {
      float4 v = ((const float4*)feat)[tid];
      ushort4 o;
      o.x = f2bf(v.x); o.y = f2bf(v.y); o.z = f2bf(v.z); o.w = f2bf(v.w);
      ((ushort4*)featb)[tid] = o;
    } else if (tid < 1600000 + 49152) {
      int t = tid - 1600000;
      int r = t >> 14, rem = t & 16383, n = rem >> 7, k = rem & 127;
      w1t[t] = f2bf(W1[(r << 14) + (k << 7) + n]);
    } else if (tid < 1600000 + 49152 + 24576) {
      int t = tid - 1649152;
      int r = t >> 13, rem = t & 8191, n = rem >> 7, k = rem & 127;
      w2t[t] = f2bf(W2[(r << 13) + (k << 6) + n]);
    }
  }
}

// ---- per-(layer,bucket) scan of 294 chunk counts (in place) + bucket totals ----
__global__ __launch_bounds__(320) void scanb_k(int* __restrict__ ghist,
                                               int* __restrict__ btot) {
  __shared__ int wsum[5];
  int t = threadIdx.x, lane = t & 63, w = t >> 6;
  int base = blockIdx.x * NCH;
  int v = (t < NCH) ? ghist[base + t] : 0;
  int inc = v;
#pragma unroll
  for (int o = 1; o < 64; o <<= 1) {
    int u = __shfl_up(inc, o);
    if (lane >= o) inc += u;
  }
  if (lane == 63) wsum[w] = inc;
  __syncthreads();
  int woff = 0;
#pragma unroll
  for (int k = 0; k < 5; ++k) if (k < w) woff += wsum[k];
  if (t < NCH) ghist[base + t] = woff + inc - v;
  if (t == 319) btot[blockIdx.x] = woff + inc;
}

// ---- single-wave scan of the 782 bucket totals -> bucket bases + sentinel ----
__global__ __launch_bounds__(64) void scanc_k(const int* __restrict__ btot,
                                              int* __restrict__ bbase) {
  int lane = threadIdx.x;
  int carry = 0;
  for (int g0 = 0; g0 < 832; g0 += 64) {
    int i = g0 + lane;
    int v = (i < 2 * NB) ? btot[i] : 0;
    int inc = v;
#pragma unroll
    for (int o = 1; o < 64; o <<= 1) {
      int u = __shfl_up(inc, o);
      if (lane >= o) inc += u;
    }
    if (i < 2 * NB) bbase[i] = carry + inc - v;
    carry += __shfl(inc, 63);
  }
  if (lane == 0) bbase[2 * NB] = carry;
}

// ---- chunk-local LDS-cursor scatter -> sorted[] (src | within-bucket-key<<16) ----
__global__ __launch_bounds__(1024) void scatter_k(
    const int* __restrict__ es1, const int* __restrict__ ed1,
    const int* __restrict__ es2, const int* __restrict__ ed2,
    const int* __restrict__ ghist, const int* __restrict__ bbase,
    unsigned* __restrict__ sorted) {
  __shared__ int cur[NB];
  int tid = threadIdx.x;
  int layer = blockIdx.x >= NCH;
  int c = blockIdx.x - layer * NCH;
  const int* es = layer ? es2 : es1;
  const int* ed = layer ? ed2 : ed1;
  if (tid < NB)
    cur[tid] = bbase[layer * NB + tid] + ghist[(layer * NB + tid) * NCH + c];
  __syncthreads();
  int j0 = c * CH;
  for (int it = 0; it < CH / 1024; ++it) {
    int j = j0 + it * 1024 + tid;
    if (j < 2400000) {
      int key = ed[j] * 4 + j / 800000;
      int pos = atomicAdd(&cur[key >> 9], 1);
      sorted[pos] = (unsigned)es[j] | ((unsigned)(key & 511) << 16);
    }
  }
}

// ---- per-bucket micro-sort: bucket-grouped -> key-sorted ushort srcs + off/cnt ----
__global__ __launch_bounds__(512) void sortb_k(
    const int* __restrict__ bbase, const unsigned* __restrict__ sorted,
    unsigned short* __restrict__ sorted2, int* __restrict__ offk,
    int* __restrict__ cntk) {
  __shared__ int hist[512], cur[512];
  int tid = threadIdx.x;
  int layer = blockIdx.x >= NB;
  int b = blockIdx.x - layer * NB;
  int start = bbase[blockIdx.x];
  int end = bbase[blockIdx.x + 1];
  hist[tid] = 0;
  __syncthreads();
  for (int e = start + tid; e < end; e += 512)
    atomicAdd(&hist[sorted[e] >> 16], 1);
  __syncthreads();
  if (tid < 64) {
    int carry = 0;
    for (int g0 = 0; g0 < 512; g0 += 64) {
      int h = hist[g0 + tid];
      int inc = h;
#pragma unroll
      for (int o = 1; o < 64; o <<= 1) {
        int u = __shfl_up(inc, o);
        if (tid >= o) inc += u;
      }
      int excl = carry + inc - h;
      cur[g0 + tid] = excl;
      int lb = layer * NKP + (b << 9) + g0 + tid;
      offk[lb] = start + excl;
      cntk[lb] = h;
      carry += __shfl(inc, 63);
    }
  }
  __syncthreads();
  for (int e = start + tid; e < end; e += 512) {
    unsigned v = sorted[e];
    int p = atomicAdd(&cur[v >> 16], 1);
    sorted2[start + p] = (unsigned short)(v & 0xFFFFu);
  }
}

// ---- layer-1 agg: wave per node, 2 edges per vmem instr (uint2/lane) ----
__global__ __launch_bounds__(256) void agg1_k(
    const int* __restrict__ offk, const int* __restrict__ cntk,
    const unsigned short* __restrict__ sorted2,
    const uint2* __restrict__ fb2, uint2* __restrict__ s1m2) {
  int lane = threadIdx.x & 63;
  int half = lane >> 5, l32 = lane & 31;
  int v = blockIdx.x * 4 + (threadIdx.x >> 6);
  if (v >= 50000) return;
  const uint2* fb = fb2 + l32;
#pragma unroll
  for (int r = 0; r < 3; ++r) {
    int key = v * 4 + r;
    int base = offk[key], n = cntk[key];
    float a0 = 0.f, a1 = 0.f, a2 = 0.f, a3 = 0.f;
    for (int jb = 0; jb < n; jb += 64) {
      int m = n - jb; if (m > 64) m = 64;
      int my = (lane < m) ? (int)sorted2[base + jb + lane] : 0;
      int k = 0;
      for (; k + 8 <= m; k += 8) {
        int i0 = __shfl(my, k + half);
        int i1 = __shfl(my, k + 2 + half);
        int i2 = __shfl(my, k + 4 + half);
        int i3 = __shfl(my, k + 6 + half);
        uint2 p0 = fb[i0 << 5], p1 = fb[i1 << 5];
        uint2 p2 = fb[i2 << 5], p3 = fb[i3 << 5];
        a0 += blo(p0.x) + blo(p1.x) + blo(p2.x) + blo(p3.x);
        a1 += bhi(p0.x) + bhi(p1.x) + bhi(p2.x) + bhi(p3.x);
        a2 += blo(p0.y) + blo(p1.y) + blo(p2.y) + blo(p3.y);
        a3 += bhi(p0.y) + bhi(p1.y) + bhi(p2.y) + bhi(p3.y);
      }
      for (; k + 2 <= m; k += 2) {
        int i0 = __shfl(my, k + half);
        uint2 p = fb[i0 << 5];
        a0 += blo(p.x); a1 += bhi(p.x); a2 += blo(p.y); a3 += bhi(p.y);
      }
      if (k < m) {
        int i0 = __shfl(my, k);
        if (half == 0) {
          uint2 p = fb[i0 << 5];
          a0 += blo(p.x); a1 += bhi(p.x); a2 += blo(p.y); a3 += bhi(p.y);
        }
      }
    }
    a0 += __shfl_xor(a0, 32); a1 += __shfl_xor(a1, 32);
    a2 += __shfl_xor(a2, 32); a3 += __shfl_xor(a3, 32);
    float inv = 1.0f / fmaxf((float)n, 1.0f);
    if (half == 0) {
      uint2 o;
      o.x = ((unsigned)f2bf(a1 * inv) << 16) | (unsigned)f2bf(a0 * inv);
      o.y = ((unsigned)f2bf(a3 * inv) << 16) | (unsigned)f2bf(a2 * inv);
      s1m2[(r * 50000 + v) * 32 + l32] = o;
    }
  }
}

// ---- fused GEMM1+GEMM2, persistent weights in registers, grid-stride M ----
// 512 blocks x 8 waves. gemm1: wave w owns h cols [16w,16w+16) -> B1 12 frags
// resident. gemm2: wave w owns Wh2 frags {w} and (w<4) {w+8} -> B2 resident.
// Per 16-row tile: 12 independent A-loads (L1-shared across waves), 1 barrier.
__global__ __launch_bounds__(512) void gemm12_k(
    const unsigned short* __restrict__ s1m, const int* __restrict__ cntk,
    const unsigned short* __restrict__ w1t, const float* __restrict__ b1,
    const unsigned short* __restrict__ w2t, const float* __restrict__ b2,
    unsigned short* __restrict__ wh2) {
  __shared__ unsigned short hs[2][16 * 136];
  int lane = threadIdx.x & 63;
  int w = threadIdx.x >> 6;             // 0..7
  int m16 = lane & 15, kg = lane >> 4;
  int orow = kg << 2;

  // ---- persistent B1: cols [16w,16w+16), all 12 k-steps ----
  short8 B1[12];
#pragma unroll
  for (int ks = 0; ks < 12; ++ks) {
    int r = ks >> 2;
    int k0 = ((ks & 3) << 5) + (kg << 3);
    int n = (w << 4) + m16;
    B1[ks] = *(const short8*)(w1t + (r << 14) + (n << 7) + k0);
  }
  // ---- persistent B2: frag fa=w (all waves), frag fb=w+8 (waves 0..3) ----
  int fa = w, fb = w + 8;
  int cola = (fa << 4) + m16, colb = (fb << 4) + m16;
  int ra = cola >> 6, c0a = cola & 63;
  int rb = colb >> 6, c0b = colb & 63;
  short8 B2a[4], B2b[4];
#pragma unroll
  for (int ks = 0; ks < 4; ++ks) {
    int k0 = (ks << 5) + (kg << 3);
    B2a[ks] = *(const short8*)(w2t + (ra << 13) + (c0a << 7) + k0);
    if (w < 4)
      B2b[ks] = *(const short8*)(w2t + (rb << 13) + (c0b << 7) + k0);
  }
  // ---- hoisted biases ----
  int col1 = (w << 4) + m16;
  float bb0 = b1[col1], bb1 = b1[128 + col1], bb2 = b1[256 + col1];
  float bva = b2[(ra << 6) + c0a];
  float bvb = (w < 4) ? b2[(rb << 6) + c0b] : 0.f;

  const floatx4 fzero = {0.f, 0.f, 0.f, 0.f};
  int p = 0;
  for (int t = blockIdx.x; t < 3125; t += 512) {
    int rbase = t << 4;
    int anode = rbase + m16;
    floatx4 acc1 = fzero;
#pragma unroll
    for (int ks = 0; ks < 12; ++ks) {
      int r = ks >> 2;
      int k0 = ((ks & 3) << 5) + (kg << 3);
      short8 af = *(const short8*)(s1m + ((r * 50000 + anode) << 7) + k0);
      acc1 = __builtin_amdgcn_mfma_f32_16x16x32_bf16(af, B1[ks], acc1, 0, 0, 0);
    }
#pragma unroll
    for (int reg = 0; reg < 4; ++reg) {
      int nd = rbase + orow + reg;
      float v = acc1[reg] + (cntk[nd * 4 + 0] ? bb0 : 0.f) +
                (cntk[nd * 4 + 1] ? bb1 : 0.f) + (cntk[nd * 4 + 2] ? bb2 : 0.f);
      v = (v >= 0.f) ? v : 0.01f * v;
      hs[p][(orow + reg) * 136 + col1] = f2bf(v);
    }
    __syncthreads();

    floatx4 acc2a = fzero, acc2b = fzero;
#pragma unroll
    for (int ks = 0; ks < 4; ++ks) {
      int k0 = (ks << 5) + (kg << 3);
      short8 af = *(const short8*)(&hs[p][m16 * 136 + k0]);
      acc2a = __builtin_amdgcn_mfma_f32_16x16x32_bf16(af, B2a[ks], acc2a, 0, 0, 0);
      if (w < 4)
        acc2b = __builtin_amdgcn_mfma_f32_16x16x32_bf16(af, B2b[ks], acc2b, 0, 0, 0);
    }
#pragma unroll
    for (int reg = 0; reg < 4; ++reg) {
      int nd = rbase + orow + reg;
      wh2[((ra * 50000 + nd) << 6) + c0a] = f2bf(acc2a[reg] + bva);
      if (w < 4)
        wh2[((rb * 50000 + nd) << 6) + c0b] = f2bf(acc2b[reg] + bvb);
    }
    p ^= 1;
  }
}

// ---- layer-2 agg + final: wave per node, 2 edges per vmem instr (uint/lane) ----
__global__ __launch_bounds__(256) void agg2f_k(
    const int* __restrict__ offk, const int* __restrict__ cntk,
    const unsigned short* __restrict__ sorted2,
    const unsigned* __restrict__ wh24, float* __restrict__ out) {
  int lane = threadIdx.x & 63;
  int half = lane >> 5, l32 = lane & 31;
  int v = blockIdx.x * 4 + (threadIdx.x >> 6);
  if (v >= 50000) return;
  const unsigned* wb = wh24 + l32;
  float o0 = 0.f, o1 = 0.f;
#pragma unroll
  for (int r = 0; r < 3; ++r) {
    int key = NKP + v * 4 + r;
    int base = offk[key], n = cntk[key];
    const unsigned* wbr = wb + r * 1600000;   // r*50000*32
    float a0 = 0.f, a1 = 0.f;
    for (int jb = 0; jb < n; jb += 64) {
      int m = n - jb; if (m > 64) m = 64;
      int my = (lane < m) ? (int)sorted2[base + jb + lane] : 0;
      int k = 0;
      for (; k + 8 <= m; k += 8) {
        int i0 = __shfl(my, k + half);
        int i1 = __shfl(my, k + 2 + half);
        int i2 = __shfl(my, k + 4 + half);
        int i3 = __shfl(my, k + 6 + half);
        unsigned p0 = wbr[i0 << 5], p1 = wbr[i1 << 5];
        unsigned p2 = wbr[i2 << 5], p3 = wbr[i3 << 5];
        a0 += blo(p0) + blo(p1) + blo(p2) + blo(p3);
        a1 += bhi(p0) + bhi(p1) + bhi(p2) + bhi(p3);
      }
      for (; k + 2 <= m; k += 2) {
        unsigned p = wbr[__shfl(my, k + half) << 5];
        a0 += blo(p); a1 += bhi(p);
      }
      if (k < m) {
        int i0 = __shfl(my, k);
        if (half == 0) {
          unsigned p = wbr[i0 << 5];
          a0 += blo(p); a1 += bhi(p);
        }
      }
    }
    a0 += __shfl_xor(a0, 32); a1 += __shfl_xor(a1, 32);
    float inv = 1.0f / fmaxf((float)n, 1.0f);
    o0 += a0 * inv; o1 += a1 * inv;
  }
  if (half == 0) {
    float2 o; o.x = o0; o.y = o1;
    ((float2*)out)[v * 32 + l32] = o;
  }
}

extern "C" void kernel_launch(void* const* d_in, const int* in_sizes, int n_in,
                              void* d_out, int out_size, void* d_ws, size_t ws_size,
                              hipStream_t stream) {
  const float* feat = (const float*)d_in[0];
  const float* W1   = (const float*)d_in[1];
  const float* b1   = (const float*)d_in[2];
  const float* W2   = (const float*)d_in[3];
  const float* b2   = (const float*)d_in[4];
  const int* es1 = (const int*)d_in[5];
  const int* ed1 = (const int*)d_in[6];
  const int* es2 = (const int*)d_in[7];
  const int* ed2 = (const int*)d_in[8];

  char* ws = (char*)d_ws;
  int* ghist           = (int*)(ws + 0);             // 229,908 ints = 919,632 B
  int* btot            = (int*)(ws + 920000);        // 782 ints
  int* bbase           = (int*)(ws + 924000);        // 783 ints
  unsigned* sorted     = (unsigned*)(ws + 928000);   // 19.2 MB
  unsigned short* sorted2 = (unsigned short*)(ws + 20128000); // 9.6 MB
  int* offk            = (int*)(ws + 29728000);      // 2*200192 ints
  int* cntk            = (int*)(ws + 31329536);      // 2*200192 ints
  unsigned short* featb = (unsigned short*)(ws + 32931072);  // 12.8 MB
  unsigned short* s1m   = (unsigned short*)(ws + 45731072);  // 38.4 MB
  unsigned short* wh2   = (unsigned short*)(ws + 84131072);  // 19.2 MB
  unsigned short* w1t   = (unsigned short*)(ws + 103331072); // 98,304 B
  unsigned short* w2t   = (unsigned short*)(ws + 103429376); // 49,152 B

  prep_count_k<<<2 * NCH + 1635, 1024, 0, stream>>>(feat, W1, W2, ed1, ed2,
                                                    featb, w1t, w2t, ghist);
  scanb_k<<<2 * NB, 320, 0, stream>>>(ghist, btot);
  scanc_k<<<1, 64, 0, stream>>>(btot, bbase);
  scatter_k<<<2 * NCH, 1024, 0, stream>>>(es1, ed1, es2, ed2, ghist, bbase, sorted);
  sortb_k<<<2 * NB, 512, 0, stream>>>(bbase, sorted, sorted2, offk, cntk);
  agg1_k<<<12500, 256, 0, stream>>>(offk, cntk, sorted2, (const uint2*)featb,
                                    (uint2*)s1m);
  gemm12_k<<<512, 512, 0, stream>>>(s1m, cntk, w1t, b1, w2t, b2, wh2);
  agg2f_k<<<12500, 256, 0, stream>>>(offk, cntk, sorted2, (const unsigned*)wh2,
                                     (float*)d_out);
}